// Round 1
// 22295.811 us; speedup vs baseline: 1.0400x; 1.0400x over previous
//
#include <hip/hip_runtime.h>

// ---------------------------------------------------------------------------
// MultilayerGRU  B=64 S=1024 I=128 H=512 L=3 O=128
// Round 8: DATA-AS-FLAG recurrence. The flag protocol cost 4 serialized LLC
// latencies per hop (store-ack, flag store, flag poll, data load). Replaced
// with NaN-poison polling of the data slab itself:
//   - every timestep gets a dedicated slot (Hbuf per-t as before; new Ubuf
//     per-t, 16 MB) -> no slot reuse inside a dispatch, no re-poison races
//   - poison_k pre-fills Hb[chunk] + Ubuf with 0x7FC07FC0 via agent-scope
//     stores (LLC-visible to the sc0 sc1 polls), stream-ordered after the
//     chunk's GEMMs (which still read prev-layer Hb)
//   - consumers poll the 16KB slab with bypass loads until no dword == poison;
//     data is already in registers at detection. Producers just store (agent
//     write-through) and move on: no vmcnt ack, no flags at all.
//   - h/u values are provably non-NaN (bounded blends of sigmoid/tanh terms),
//     so 0x7FC0 bf16 can never occur in real data.
//   - tl==0 bootstrap: each WG loads full fp32 h from hstate/h0 directly
//     (inputs visible to all) -> zero cross-WG communication at chunk start.
// Everything else (64 WG = 4 batch-groups x 16 col-slices, 2 waves, LDS
// weight staging, GEMM topology, workspace offsets through hst) unchanged
// from the proven round-3/7 layout. Ubuf appended: ws end 154,796,032 B.
// ---------------------------------------------------------------------------

typedef float f32x4 __attribute__((ext_vector_type(4)));
typedef __bf16 bf16x8 __attribute__((ext_vector_type(8)));

#define CT 256   // timesteps per chunk
#define CC 32    // H-columns per workgroup slice
#define POIS 0x7FC07FC0

__device__ __forceinline__ unsigned short f2bf(float x) {
  unsigned int u = __builtin_bit_cast(unsigned int, x);
  u += 0x7fffu + ((u >> 16) & 1u);   // round-to-nearest-even
  return (unsigned short)(u >> 16);
}
__device__ __forceinline__ float bf2f(unsigned short h) {
  unsigned int u = ((unsigned int)h) << 16;
  return __builtin_bit_cast(float, u);
}
__device__ __forceinline__ f32x4 mfma16(int4 a, int4 b, f32x4 c) {
  return __builtin_amdgcn_mfma_f32_16x16x32_bf16(
      __builtin_bit_cast(bf16x8, a), __builtin_bit_cast(bf16x8, b), c, 0, 0, 0);
}
__device__ __forceinline__ float sig_(float x) { return 1.0f / (1.0f + __expf(-x)); }
__device__ __forceinline__ float tanh_(float x) {
  float ax = fabsf(x);
  float e  = __expf(2.0f * ax);
  float t  = 1.0f - 2.0f / (e + 1.0f);
  return x < 0.0f ? -t : t;
}

// ---- coherence-point (cross-XCD) access helpers ----
__device__ __forceinline__ void issue_ld16(const unsigned short* p, int4& d) {
  asm volatile("global_load_dwordx4 %0, %1, off sc0 sc1"
               : "=v"(d) : "v"(p) : "memory");
}
__device__ __forceinline__ void st_wt128(unsigned short* p, int4 v) {
  unsigned long long lo = ((unsigned long long)(unsigned int)v.y << 32) | (unsigned int)v.x;
  unsigned long long hi = ((unsigned long long)(unsigned int)v.w << 32) | (unsigned int)v.z;
  __hip_atomic_store((unsigned long long*)p,     lo, __ATOMIC_RELAXED, __HIP_MEMORY_SCOPE_AGENT);
  __hip_atomic_store((unsigned long long*)p + 1, hi, __ATOMIC_RELAXED, __HIP_MEMORY_SCOPE_AGENT);
}
__device__ __forceinline__ void wait_vm0() {
  asm volatile("s_waitcnt vmcnt(0)" ::: "memory");
}

// Poll a 16-row x 512-col bf16 slab (fragment layout: row = base+l15,
// cols kq*8 + kc*32) until no dword is poison. Data is valid on return:
// per-dword store atomicity + "value is the signal" needs no fences.
__device__ __forceinline__ void poll_slab16(const unsigned short* p, int4* d) {
  for (;;) {
#pragma unroll
    for (int kc = 0; kc < 16; kc++) issue_ld16(p + kc * 32, d[kc]);
    wait_vm0();
    int bad = 0;
#pragma unroll
    for (int kc = 0; kc < 16; kc++)
      bad |= (d[kc].x == POIS) | (d[kc].y == POIS) | (d[kc].z == POIS) | (d[kc].w == POIS);
    if (!__any(bad)) return;
  }
}

// ---------------------------------------------------------------------------
__global__ void cvt_bf16(const float* __restrict__ src, unsigned short* __restrict__ dst, int n4) {
  int i = blockIdx.x * blockDim.x + threadIdx.x;
  if (i < n4) {
    float4 v = *(const float4*)(src + (size_t)i * 4);
    ushort4 o;
    o.x = f2bf(v.x); o.y = f2bf(v.y); o.z = f2bf(v.z); o.w = f2bf(v.w);
    *(ushort4*)(dst + (size_t)i * 4) = o;
  }
}

// X (64,1024,128) f32 -> Xt row (t*64+b), 128 bf16
__global__ void xt_k(const float* __restrict__ X, unsigned short* __restrict__ Xt) {
  int idx = blockIdx.x * 256 + threadIdx.x;
  int i4 = idx & 31, rest = idx >> 5;
  int t = rest & 1023, b = rest >> 10;
  float4 v = *(const float4*)(X + (size_t)(b * 1024 + t) * 128 + i4 * 4);
  ushort4 o;
  o.x = f2bf(v.x); o.y = f2bf(v.y); o.z = f2bf(v.z); o.w = f2bf(v.w);
  *(ushort4*)(Xt + (size_t)(t * 64 + b) * 128 + i4 * 4) = o;
}

// Pre-poison Hb[chunk] (arg a) and Ubuf (arg b): 16,777,216 B each =
// 2,097,152 u64 each. Grid 2048 x 256, 4 u64 per thread per region.
// Agent-scope stores so the poison is at the coherence point (LLC) where the
// sc0 sc1 polls read -- a plain cached store could linger dirty in one XCD's
// L2 and let a poll see stale (NaN-free!) data from the previous chunk.
__global__ void poison_k(unsigned long long* __restrict__ a,
                         unsigned long long* __restrict__ b) {
  const unsigned long long P = 0x7FC07FC07FC07FC0ull;
  unsigned long long* pa = a + (size_t)blockIdx.x * 1024 + threadIdx.x;
  unsigned long long* pb = b + (size_t)blockIdx.x * 1024 + threadIdx.x;
#pragma unroll
  for (int k = 0; k < 4; k++) {
    __hip_atomic_store(pa + k * 256, P, __ATOMIC_RELAXED, __HIP_MEMORY_SCOPE_AGENT);
    __hip_atomic_store(pb + k * 256, P, __ATOMIC_RELAXED, __HIP_MEMORY_SCOPE_AGENT);
  }
}

// ---------------------------------------------------------------------------
// C[M,N] = A[M,K] @ W[N,K]^T  (bf16). mode 0: bf16 out; mode 2: fp32+bias,
// row remap m=(t*64+b) -> out row b*1024+t (final Y).   (unchanged, proven)
// ---------------------------------------------------------------------------
__global__ __launch_bounds__(256)
void gemm_bt(const unsigned short* __restrict__ A, const unsigned short* __restrict__ W,
             void* __restrict__ Cout, const float* __restrict__ bias,
             int M, int N, int K, int mode) {
  __shared__ unsigned short As[128][72];
  __shared__ unsigned short Bs[128][72];
  const int tid  = threadIdx.x;
  const int lane = tid & 63;
  const int wave = tid >> 6;
  const int wr = wave >> 1, wc = wave & 1;
  const int m0 = blockIdx.x * 128, n0 = blockIdx.y * 128;

  f32x4 acc[4][4];
  for (int i = 0; i < 4; i++)
    for (int j = 0; j < 4; j++) acc[i][j] = f32x4{0.f, 0.f, 0.f, 0.f};

  for (int k0 = 0; k0 < K; k0 += 64) {
    int4 va[4], vb[4];
#pragma unroll
    for (int it = 0; it < 4; it++) {
      int q = tid + it * 256;
      int r = q >> 3, kc = q & 7;
      va[it] = *(const int4*)(A + (size_t)(m0 + r) * K + k0 + kc * 8);
      vb[it] = *(const int4*)(W + (size_t)(n0 + r) * K + k0 + kc * 8);
    }
    __syncthreads();
#pragma unroll
    for (int it = 0; it < 4; it++) {
      int q = tid + it * 256;
      int r = q >> 3, kc = q & 7;
      *(int4*)&As[r][kc * 8] = va[it];
      *(int4*)&Bs[r][kc * 8] = vb[it];
    }
    __syncthreads();
#pragma unroll
    for (int kc = 0; kc < 2; kc++) {
      int koff = kc * 32 + (lane >> 4) * 8;
      int4 af[4], bfr[4];
#pragma unroll
      for (int mt = 0; mt < 4; mt++) af[mt]  = *(const int4*)&As[wr * 64 + mt * 16 + (lane & 15)][koff];
#pragma unroll
      for (int nt = 0; nt < 4; nt++) bfr[nt] = *(const int4*)&Bs[wc * 64 + nt * 16 + (lane & 15)][koff];
#pragma unroll
      for (int mt = 0; mt < 4; mt++)
#pragma unroll
        for (int nt = 0; nt < 4; nt++)
          acc[mt][nt] = mfma16(af[mt], bfr[nt], acc[mt][nt]);
    }
  }

#pragma unroll
  for (int mt = 0; mt < 4; mt++)
#pragma unroll
    for (int nt = 0; nt < 4; nt++)
#pragma unroll
      for (int rg = 0; rg < 4; rg++) {
        int m = m0 + wr * 64 + mt * 16 + (lane >> 4) * 4 + rg;
        int n = n0 + wc * 64 + nt * 16 + (lane & 15);
        float v = acc[mt][nt][rg];
        if (mode == 0) {
          ((unsigned short*)Cout)[(size_t)m * N + n] = f2bf(v);
        } else {
          ((float*)Cout)[(size_t)((m & 63) * 1024 + (m >> 6)) * N + n] = v + bias[n];
        }
      }
}

// ---------------------------------------------------------------------------
// Recurrence over one 256-step chunk. 64 WGs = 4 batch-groups x 16 col-slices
// (32 cols each). 2 waves: wave0 = r,z + u publish; wave1 = g + h publish.
// All cross-WG signalling is data-as-flag (NaN poison), zero fences/flags.
// ---------------------------------------------------------------------------
__global__ __launch_bounds__(128)
void gru_rec(const float* __restrict__ Whz, const float* __restrict__ Whr,
             const float* __restrict__ Whg,
             const float* __restrict__ bz, const float* __restrict__ br,
             const float* __restrict__ bg,
             const unsigned short* __restrict__ Pz, const unsigned short* __restrict__ Pr,
             const unsigned short* __restrict__ Pg,   // chunk-local (CT,B,H) bf16
             const float* __restrict__ h0,            // (B,L,H) fp32 original
             float* __restrict__ hstate,              // (B,H) fp32 carry
             unsigned short* __restrict__ Hbuf,       // (S,B,H) bf16, per-t slots (poisoned)
             unsigned short* __restrict__ Ubuf,       // (CT,B,H) bf16, per-t slots (poisoned)
             float* __restrict__ hidout,              // (B,L,H) fp32
             int layer, int tstart) {
  const int bid  = blockIdx.x;
  const int g    = bid & 3;          // batch group (16 rows)
  const int mem  = bid >> 2;         // col slice 0..15
  const int cbase = mem * CC;
  const int tid  = threadIdx.x;
  const int lane = tid & 63;
  const int wave = tid >> 6;         // 0..1

  // K-major weight LDS: [gate 0=z,1=r,2=g][K-octet 0..63][col 0..31][8 bf16]
  __shared__ unsigned short Whs[3][64][32][8];   // 98,304 B
  __shared__ float hloc[16][CC + 1];
  __shared__ float zbuf[16][CC + 1];
  __shared__ unsigned short un[16][40];
  __shared__ unsigned short hnew[16][40];

  // ---- stage Wh fp32 -> bf16 K-major LDS ----
  {
    const float* wsrc[3] = { Whz + (size_t)layer * 262144,
                             Whr + (size_t)layer * 262144,
                             Whg + (size_t)layer * 262144 };
    for (int idx = tid; idx < 12288; idx += 128) {
      int gate = idx >> 12;            // 0..2
      int r = idx & 4095;
      int c = r >> 7, k4 = r & 127;
      float4 v = *(const float4*)(wsrc[gate] + (size_t)(cbase + c) * 512 + k4 * 4);
      int o = k4 >> 1, base = (k4 & 1) * 4;
      Whs[gate][o][c][base + 0] = f2bf(v.x);
      Whs[gate][o][c][base + 1] = f2bf(v.y);
      Whs[gate][o][c][base + 2] = f2bf(v.z);
      Whs[gate][o][c][base + 3] = f2bf(v.w);
    }
  }
  // ---- init local h slice (fp32) -- no broadcast needed at tl==0 ----
  for (int q = tid; q < 16 * CC; q += 128) {
    int row = q >> 5, c = q & 31;
    int b = g * 16 + row;
    hloc[row][c] = (tstart == 0)
                     ? h0[(size_t)b * 1536 + layer * 512 + cbase + c]
                     : hstate[(size_t)b * 512 + cbase + c];
  }
  __syncthreads();

  const int l15 = lane & 15;
  const int kq  = lane >> 4;

  float bzc[2], brc[2], bgc[2];
#pragma unroll
  for (int T = 0; T < 2; T++) {
    bzc[T] = bz[(size_t)layer * 512 + cbase + T * 16 + l15];
    brc[T] = br[(size_t)layer * 512 + cbase + T * 16 + l15];
    bgc[T] = bg[(size_t)layer * 512 + cbase + T * 16 + l15];
  }

  for (int tl = 0; tl < CT; tl++) {
    if (wave == 0) {
      // ---- prefetch P (cached, independent of h) ----
      float pr[2][4], pz[2][4];
#pragma unroll
      for (int T = 0; T < 2; T++)
#pragma unroll
        for (int rg = 0; rg < 4; rg++) {
          size_t off = (size_t)tl * 32768 + (size_t)(g * 16 + kq * 4 + rg) * 512 + cbase + T * 16 + l15;
          pr[T][rg] = bf2f(Pr[off]);
          pz[T][rg] = bf2f(Pz[off]);
        }
      // ---- acquire h(t-1) fragments ----
      int4 hf[16];
      if (tl == 0) {
        // bootstrap: full fp32 h straight from inputs (visible to all WGs)
        const float* hs = (tstart == 0)
                            ? h0 + (size_t)(g * 16 + l15) * 1536 + (size_t)layer * 512
                            : hstate + (size_t)(g * 16 + l15) * 512;
#pragma unroll
        for (int kc = 0; kc < 16; kc++) {
          int c0 = kq * 8 + kc * 32;
          float4 v0 = *(const float4*)(hs + c0);
          float4 v1 = *(const float4*)(hs + c0 + 4);
          int w0 = (int)f2bf(v0.x) | ((int)f2bf(v0.y) << 16);
          int w1 = (int)f2bf(v0.z) | ((int)f2bf(v0.w) << 16);
          int w2 = (int)f2bf(v1.x) | ((int)f2bf(v1.y) << 16);
          int w3 = (int)f2bf(v1.z) | ((int)f2bf(v1.w) << 16);
          hf[kc] = int4{w0, w1, w2, w3};
        }
      } else {
        poll_slab16(Hbuf + (size_t)(tstart + tl - 1) * 32768 + (g * 16 + l15) * 512 + kq * 8, hf);
      }
      // ---- r gate first (feeds the u-hop) ----
      f32x4 ar[2] = { f32x4{0.f,0.f,0.f,0.f}, f32x4{0.f,0.f,0.f,0.f} };
#pragma unroll
      for (int kc = 0; kc < 16; kc++)
#pragma unroll
        for (int T = 0; T < 2; T++)
          ar[T] = mfma16(hf[kc], *(const int4*)&Whs[1][kc * 4 + kq][T * 16 + l15][0], ar[T]);
#pragma unroll
      for (int T = 0; T < 2; T++)
#pragma unroll
        for (int rg = 0; rg < 4; rg++) {
          int row = kq * 4 + rg, c = T * 16 + l15;
          float rv = sig_(ar[T][rg] + pr[T][rg] + brc[T]);
          un[row][c] = f2bf(rv * hloc[row][c]);
        }
      // coalesced u publish (64 lanes x 16B = 1 KB slice); value IS the flag
      {
        int4 v = *(const int4*)&un[lane >> 2][(lane & 3) * 8];
        st_wt128(Ubuf + (size_t)tl * 32768 + (g * 16 + (lane >> 2)) * 512 + cbase + (lane & 3) * 8, v);
      }
      // ---- z gate (off the u critical path; store drains in background) ----
      f32x4 az[2] = { f32x4{0.f,0.f,0.f,0.f}, f32x4{0.f,0.f,0.f,0.f} };
#pragma unroll
      for (int kc = 0; kc < 16; kc++)
#pragma unroll
        for (int T = 0; T < 2; T++)
          az[T] = mfma16(hf[kc], *(const int4*)&Whs[0][kc * 4 + kq][T * 16 + l15][0], az[T]);
#pragma unroll
      for (int T = 0; T < 2; T++)
#pragma unroll
        for (int rg = 0; rg < 4; rg++)
          zbuf[kq * 4 + rg][T * 16 + l15] = sig_(az[T][rg] + pz[T][rg] + bzc[T]);
    } else {
      // ---- prefetch Pg ----
      float pg[2][4];
#pragma unroll
      for (int T = 0; T < 2; T++)
#pragma unroll
        for (int rg = 0; rg < 4; rg++)
          pg[T][rg] = bf2f(Pg[(size_t)tl * 32768 + (size_t)(g * 16 + kq * 4 + rg) * 512 + cbase + T * 16 + l15]);
      // ---- acquire u(t): data-as-flag poll ----
      int4 uf[16];
      poll_slab16(Ubuf + (size_t)tl * 32768 + (g * 16 + l15) * 512 + kq * 8, uf);
      f32x4 ag[2] = { f32x4{0.f,0.f,0.f,0.f}, f32x4{0.f,0.f,0.f,0.f} };
#pragma unroll
      for (int kc = 0; kc < 16; kc++)
#pragma unroll
        for (int T = 0; T < 2; T++)
          ag[T] = mfma16(uf[kc], *(const int4*)&Whs[2][kc * 4 + kq][T * 16 + l15][0], ag[T]);
      // stash pre-activation + pg in ag for post-barrier blend
#pragma unroll
      for (int T = 0; T < 2; T++)
#pragma unroll
        for (int rg = 0; rg < 4; rg++)
          ag[T][rg] += pg[T][rg] + bgc[T];
      __syncthreads();   // A: zbuf ready (wave0 wrote it pre-barrier)
#pragma unroll
      for (int T = 0; T < 2; T++)
#pragma unroll
        for (int rg = 0; rg < 4; rg++) {
          int row = kq * 4 + rg, c = T * 16 + l15;
          float gv = tanh_(ag[T][rg]);
          float z  = zbuf[row][c];
          float h  = hloc[row][c];
          float hn = z * h + (1.0f - z) * gv;
          hloc[row][c] = hn;
          hnew[row][c] = f2bf(hn);
        }
      // coalesced h publish: agent write-through so both the t+1 polls (LLC)
      // and the next layer's GEMMs see it. Value IS the flag.
      {
        int4 v = *(const int4*)&hnew[lane >> 2][(lane & 3) * 8];
        st_wt128(&Hbuf[(size_t)(tstart + tl) * 32768 + (g * 16 + (lane >> 2)) * 512 + cbase + (lane & 3) * 8], v);
      }
    }
    if (wave == 0) __syncthreads();  // A (wave0 side)
    __syncthreads();                 // B: hloc/zbuf safe for next step
  }

  // ---- chunk carry-out ----
  for (int q = tid; q < 16 * CC; q += 128) {
    int row = q >> 5, c = q & 31;
    int b = g * 16 + row;
    float v = hloc[row][c];
    hstate[(size_t)b * 512 + cbase + c] = v;
    if (tstart + CT == 1024)
      hidout[(size_t)b * 1536 + layer * 512 + cbase + c] = v;
  }
}

// ---------------------------------------------------------------------------
// launcher
// ---------------------------------------------------------------------------
extern "C" void kernel_launch(void* const* d_in, const int* in_sizes, int n_in,
                              void* d_out, int out_size, void* d_ws, size_t ws_size,
                              hipStream_t stream) {
  const float* X    = (const float*)d_in[0];
  const float* H0   = (const float*)d_in[1];
  const float* Wx0z = (const float*)d_in[2];
  const float* Wx0r = (const float*)d_in[3];
  const float* Wx0g = (const float*)d_in[4];
  const float* Wxz  = (const float*)d_in[5];
  const float* Wxr  = (const float*)d_in[6];
  const float* Wxg  = (const float*)d_in[7];
  const float* Whz  = (const float*)d_in[8];
  const float* Whr  = (const float*)d_in[9];
  const float* Whg  = (const float*)d_in[10];
  const float* bz   = (const float*)d_in[11];
  const float* br   = (const float*)d_in[12];
  const float* bg   = (const float*)d_in[13];
  const float* Wy   = (const float*)d_in[14];
  const float* by   = (const float*)d_in[15];

  char* w = (char*)d_ws;
  unsigned short* Xt    = (unsigned short*)(w + 0);          // 16,777,216
  unsigned short* Wx0zb = (unsigned short*)(w + 16777216);   // 131,072
  unsigned short* Wx0rb = (unsigned short*)(w + 16908288);
  unsigned short* Wx0gb = (unsigned short*)(w + 17039360);
  unsigned short* Wxzb  = (unsigned short*)(w + 17170432);   // 1,048,576
  unsigned short* Wxrb  = (unsigned short*)(w + 18219008);
  unsigned short* Wxgb  = (unsigned short*)(w + 19267584);
  unsigned short* Wyb   = (unsigned short*)(w + 20316160);   // 131,072
  unsigned short* Pz    = (unsigned short*)(w + 20447232);   // 16,777,216 each
  unsigned short* Pr    = (unsigned short*)(w + 37224448);
  unsigned short* Pg    = (unsigned short*)(w + 54001664);
  unsigned short* Hb    = (unsigned short*)(w + 70778880);   // 67,108,864
  float*          hst   = (float*)(w + 137887744);           // 131,072
  unsigned short* Ubuf  = (unsigned short*)(w + 138018816);  // 16,777,216
  // end 154,796,032 bytes (grew by Ubuf; flag/bcast buffers removed)

  auto cvt = [&](const float* s, unsigned short* d, int n) {
    int n4 = n / 4;
    cvt_bf16<<<dim3((n4 + 255) / 256), dim3(256), 0, stream>>>(s, d, n4);
  };
  xt_k<<<dim3(8192), dim3(256), 0, stream>>>(X, Xt);
  cvt(Wx0z, Wx0zb, 65536);
  cvt(Wx0r, Wx0rb, 65536);
  cvt(Wx0g, Wx0gb, 65536);
  cvt(Wxz, Wxzb, 524288);
  cvt(Wxr, Wxrb, 524288);
  cvt(Wxg, Wxgb, 524288);
  cvt(Wy, Wyb, 65536);

  float* hidout = (float*)d_out + 8388608;

  for (int layer = 0; layer < 3; layer++) {
    for (int chunk = 0; chunk < 4; chunk++) {
      int tstart = chunk * CT;
      const unsigned short *Ap, *wz, *wr_, *wg;
      int K;
      if (layer == 0) {
        Ap = Xt + (size_t)tstart * 64 * 128;
        wz = Wx0zb; wr_ = Wx0rb; wg = Wx0gb; K = 128;
      } else {
        Ap = Hb + (size_t)tstart * 64 * 512;
        wz = Wxzb + (size_t)(layer - 1) * 262144;
        wr_ = Wxrb + (size_t)(layer - 1) * 262144;
        wg = Wxgb + (size_t)(layer - 1) * 262144;
        K = 512;
      }
      gemm_bt<<<dim3(128, 4), 256, 0, stream>>>(Ap, wz,  Pz, (const float*)nullptr, 16384, 512, K, 0);
      gemm_bt<<<dim3(128, 4), 256, 0, stream>>>(Ap, wr_, Pr, (const float*)nullptr, 16384, 512, K, 0);
      gemm_bt<<<dim3(128, 4), 256, 0, stream>>>(Ap, wg,  Pg, (const float*)nullptr, 16384, 512, K, 0);

      // poison AFTER the GEMMs (which read prev-layer Hb[chunk]) and BEFORE
      // the recurrence that polls these regions. Stream order = happens-before.
      poison_k<<<dim3(2048), dim3(256), 0, stream>>>(
          (unsigned long long*)(Hb + (size_t)tstart * 32768),
          (unsigned long long*)Ubuf);

      gru_rec<<<dim3(64), dim3(128), 0, stream>>>(
          Whz, Whr, Whg, bz, br, bg, Pz, Pr, Pg, H0, hst, Hb, Ubuf,
          hidout, layer, tstart);
    }
  }

  // Y = H2 @ Wy^T + by  -> (B,S,O) fp32
  gemm_bt<<<dim3(512, 1), 256, 0, stream>>>(Hb, Wyb, d_out, by, 65536, 128, 512, 2);
}

// Round 3
// 14238.405 us; speedup vs baseline: 1.6285x; 1.5659x over previous
//
#include <hip/hip_runtime.h>

// ---------------------------------------------------------------------------
// MultilayerGRU  B=64 S=1024 I=128 H=512 L=3 O=128
// Round 10: round-9 wavefront schedule with the P-slot stride bug fixed.
// Round-9 failure analysis: launcher writes slot s's gate buffers at byte
// stride PBLK=50,331,648 (3 gates x 16 MB), but gru_rec read them at stride
// 16 MB -> slot 1 read Pr as Pz (etc). Slot 0 agreed, so serial/width-1 paths
// were correct; multi-cell diagonals mixed gates -> absmax 0.29. Fix: use the
// same 25,165,824-short stride in the kernel. Schedule re-audited: all Hb
// chunk read/write/poison and hstate carries are stream-ordered, no races.
//
// Design (unchanged): cells (l,c) of the 3x4 (layer,chunk) grid on one
// anti-diagonal are independent; 12 serial recurrence dispatches -> 6
// diagonal dispatches of 1-3 independent 64-WG cells (<=192 WGs, 1 WG/CU).
// Cell internals are byte-identical to round 8 (data-as-flag NaN-poison
// polling, zero fences). Workspace tiers: 3-slot 289.3 MB / 2-slot 222.2 MB
// / serial 154.8 MB (== round-8 proven layout), picked from ws_size.
// ---------------------------------------------------------------------------

typedef float f32x4 __attribute__((ext_vector_type(4)));
typedef __bf16 bf16x8 __attribute__((ext_vector_type(8)));

#define CT 256   // timesteps per chunk
#define CC 32    // H-columns per workgroup slice
#define POIS 0x7FC07FC0
#define PSLOT_SHORTS 25165824ull   // 50,331,648 B per P slot (3 gates x 16 MB)
#define USLOT_SHORTS 8388608ull    // 16,777,216 B per U slot

struct RecMeta {
  int l[3];     // layer per cell
  int ts[3];    // tstart per cell
  int slot[3];  // P/U slot per cell
  int hstStride; // floats between per-layer hstate copies (0 in serial tier)
};

__device__ __forceinline__ unsigned short f2bf(float x) {
  unsigned int u = __builtin_bit_cast(unsigned int, x);
  u += 0x7fffu + ((u >> 16) & 1u);   // round-to-nearest-even
  return (unsigned short)(u >> 16);
}
__device__ __forceinline__ float bf2f(unsigned short h) {
  unsigned int u = ((unsigned int)h) << 16;
  return __builtin_bit_cast(float, u);
}
__device__ __forceinline__ f32x4 mfma16(int4 a, int4 b, f32x4 c) {
  return __builtin_amdgcn_mfma_f32_16x16x32_bf16(
      __builtin_bit_cast(bf16x8, a), __builtin_bit_cast(bf16x8, b), c, 0, 0, 0);
}
__device__ __forceinline__ float sig_(float x) { return 1.0f / (1.0f + __expf(-x)); }
__device__ __forceinline__ float tanh_(float x) {
  float ax = fabsf(x);
  float e  = __expf(2.0f * ax);
  float t  = 1.0f - 2.0f / (e + 1.0f);
  return x < 0.0f ? -t : t;
}

// ---- coherence-point (cross-XCD) access helpers ----
__device__ __forceinline__ void issue_ld16(const unsigned short* p, int4& d) {
  asm volatile("global_load_dwordx4 %0, %1, off sc0 sc1"
               : "=v"(d) : "v"(p) : "memory");
}
__device__ __forceinline__ void st_wt128(unsigned short* p, int4 v) {
  unsigned long long lo = ((unsigned long long)(unsigned int)v.y << 32) | (unsigned int)v.x;
  unsigned long long hi = ((unsigned long long)(unsigned int)v.w << 32) | (unsigned int)v.z;
  __hip_atomic_store((unsigned long long*)p,     lo, __ATOMIC_RELAXED, __HIP_MEMORY_SCOPE_AGENT);
  __hip_atomic_store((unsigned long long*)p + 1, hi, __ATOMIC_RELAXED, __HIP_MEMORY_SCOPE_AGENT);
}
__device__ __forceinline__ void wait_vm0() {
  asm volatile("s_waitcnt vmcnt(0)" ::: "memory");
}

// Poll a 16-row x 512-col bf16 slab until no dword is poison. Data is valid
// in d[] on return: per-dword store atomicity, the value IS the signal.
__device__ __forceinline__ void poll_slab16(const unsigned short* p, int4* d) {
  for (;;) {
#pragma unroll
    for (int kc = 0; kc < 16; kc++) issue_ld16(p + kc * 32, d[kc]);
    wait_vm0();
    int bad = 0;
#pragma unroll
    for (int kc = 0; kc < 16; kc++)
      bad |= (d[kc].x == POIS) | (d[kc].y == POIS) | (d[kc].z == POIS) | (d[kc].w == POIS);
    if (!__any(bad)) return;
  }
}

// ---------------------------------------------------------------------------
__global__ void cvt_bf16(const float* __restrict__ src, unsigned short* __restrict__ dst, int n4) {
  int i = blockIdx.x * blockDim.x + threadIdx.x;
  if (i < n4) {
    float4 v = *(const float4*)(src + (size_t)i * 4);
    ushort4 o;
    o.x = f2bf(v.x); o.y = f2bf(v.y); o.z = f2bf(v.z); o.w = f2bf(v.w);
    *(ushort4*)(dst + (size_t)i * 4) = o;
  }
}

// X (64,1024,128) f32 -> Xt row (t*64+b), 128 bf16
__global__ void xt_k(const float* __restrict__ X, unsigned short* __restrict__ Xt) {
  int idx = blockIdx.x * 256 + threadIdx.x;
  int i4 = idx & 31, rest = idx >> 5;
  int t = rest & 1023, b = rest >> 10;
  float4 v = *(const float4*)(X + (size_t)(b * 1024 + t) * 128 + i4 * 4);
  ushort4 o;
  o.x = f2bf(v.x); o.y = f2bf(v.y); o.z = f2bf(v.z); o.w = f2bf(v.w);
  *(ushort4*)(Xt + (size_t)(t * 64 + b) * 128 + i4 * 4) = o;
}

// Pre-poison one Hb chunk (a) and one Ubuf slot (b): 16,777,216 B each.
// Agent-scope stores so poison is at the coherence point the polls read.
__global__ void poison_k(unsigned long long* __restrict__ a,
                         unsigned long long* __restrict__ b) {
  const unsigned long long P = 0x7FC07FC07FC07FC0ull;
  unsigned long long* pa = a + (size_t)blockIdx.x * 1024 + threadIdx.x;
  unsigned long long* pb = b + (size_t)blockIdx.x * 1024 + threadIdx.x;
#pragma unroll
  for (int k = 0; k < 4; k++) {
    __hip_atomic_store(pa + k * 256, P, __ATOMIC_RELAXED, __HIP_MEMORY_SCOPE_AGENT);
    __hip_atomic_store(pb + k * 256, P, __ATOMIC_RELAXED, __HIP_MEMORY_SCOPE_AGENT);
  }
}

// ---------------------------------------------------------------------------
// C[M,N] = A[M,K] @ W[N,K]^T  (bf16). mode 0: bf16 out; mode 2: fp32+bias,
// row remap m=(t*64+b) -> out row b*1024+t (final Y).   (unchanged, proven)
// ---------------------------------------------------------------------------
__global__ __launch_bounds__(256)
void gemm_bt(const unsigned short* __restrict__ A, const unsigned short* __restrict__ W,
             void* __restrict__ Cout, const float* __restrict__ bias,
             int M, int N, int K, int mode) {
  __shared__ unsigned short As[128][72];
  __shared__ unsigned short Bs[128][72];
  const int tid  = threadIdx.x;
  const int lane = tid & 63;
  const int wave = tid >> 6;
  const int wr = wave >> 1, wc = wave & 1;
  const int m0 = blockIdx.x * 128, n0 = blockIdx.y * 128;

  f32x4 acc[4][4];
  for (int i = 0; i < 4; i++)
    for (int j = 0; j < 4; j++) acc[i][j] = f32x4{0.f, 0.f, 0.f, 0.f};

  for (int k0 = 0; k0 < K; k0 += 64) {
    int4 va[4], vb[4];
#pragma unroll
    for (int it = 0; it < 4; it++) {
      int q = tid + it * 256;
      int r = q >> 3, kc = q & 7;
      va[it] = *(const int4*)(A + (size_t)(m0 + r) * K + k0 + kc * 8);
      vb[it] = *(const int4*)(W + (size_t)(n0 + r) * K + k0 + kc * 8);
    }
    __syncthreads();
#pragma unroll
    for (int it = 0; it < 4; it++) {
      int q = tid + it * 256;
      int r = q >> 3, kc = q & 7;
      *(int4*)&As[r][kc * 8] = va[it];
      *(int4*)&Bs[r][kc * 8] = vb[it];
    }
    __syncthreads();
#pragma unroll
    for (int kc = 0; kc < 2; kc++) {
      int koff = kc * 32 + (lane >> 4) * 8;
      int4 af[4], bfr[4];
#pragma unroll
      for (int mt = 0; mt < 4; mt++) af[mt]  = *(const int4*)&As[wr * 64 + mt * 16 + (lane & 15)][koff];
#pragma unroll
      for (int nt = 0; nt < 4; nt++) bfr[nt] = *(const int4*)&Bs[wc * 64 + nt * 16 + (lane & 15)][koff];
#pragma unroll
      for (int mt = 0; mt < 4; mt++)
#pragma unroll
        for (int nt = 0; nt < 4; nt++)
          acc[mt][nt] = mfma16(af[mt], bfr[nt], acc[mt][nt]);
    }
  }

#pragma unroll
  for (int mt = 0; mt < 4; mt++)
#pragma unroll
    for (int nt = 0; nt < 4; nt++)
#pragma unroll
      for (int rg = 0; rg < 4; rg++) {
        int m = m0 + wr * 64 + mt * 16 + (lane >> 4) * 4 + rg;
        int n = n0 + wc * 64 + nt * 16 + (lane & 15);
        float v = acc[mt][nt][rg];
        if (mode == 0) {
          ((unsigned short*)Cout)[(size_t)m * N + n] = f2bf(v);
        } else {
          ((float*)Cout)[(size_t)((m & 63) * 1024 + (m >> 6)) * N + n] = v + bias[n];
        }
      }
}

// ---------------------------------------------------------------------------
// Recurrence: up to 3 independent (layer,chunk) cells per dispatch.
// Cell = blockIdx.x>>6 (64 WGs each = 4 batch-groups x 16 col-slices).
// Cell internals identical to round 8 (data-as-flag, NaN-poison polling).
// ---------------------------------------------------------------------------
__global__ __launch_bounds__(128)
void gru_rec(const float* __restrict__ Whz, const float* __restrict__ Whr,
             const float* __restrict__ Whg,
             const float* __restrict__ bz, const float* __restrict__ br,
             const float* __restrict__ bg,
             const unsigned short* __restrict__ PzB, const unsigned short* __restrict__ PrB,
             const unsigned short* __restrict__ PgB, // slot-strided bases
             const float* __restrict__ h0,           // (B,L,H) fp32 original
             float* __restrict__ hstateB,            // per-layer (B,H) fp32 carries
             unsigned short* __restrict__ Hbuf,      // (S,B,H) bf16, per-t slots (poisoned)
             unsigned short* __restrict__ UbufB,     // slot-strided (CT,B,H) bf16 (poisoned)
             float* __restrict__ hidout,             // (B,L,H) fp32
             RecMeta meta) {
  const int cell = blockIdx.x >> 6;
  const int bid  = blockIdx.x & 63;
  const int layer  = meta.l[cell];
  const int tstart = meta.ts[cell];
  const int slot   = meta.slot[cell];
  // FIX(r10): P slot stride must match the launcher's PBLK layout
  // (50,331,648 B per slot = 25,165,824 shorts), NOT the 16 MB gate size.
  const unsigned short* Pz = PzB + (size_t)slot * PSLOT_SHORTS;
  const unsigned short* Pr = PrB + (size_t)slot * PSLOT_SHORTS;
  const unsigned short* Pg = PgB + (size_t)slot * PSLOT_SHORTS;
  unsigned short* Ubuf     = UbufB + (size_t)slot * USLOT_SHORTS;
  float* hstate            = hstateB + (size_t)layer * meta.hstStride;

  const int g    = bid & 3;          // batch group (16 rows)
  const int mem  = bid >> 2;         // col slice 0..15
  const int cbase = mem * CC;
  const int tid  = threadIdx.x;
  const int lane = tid & 63;
  const int wave = tid >> 6;         // 0..1

  // K-major weight LDS: [gate 0=z,1=r,2=g][K-octet 0..63][col 0..31][8 bf16]
  __shared__ unsigned short Whs[3][64][32][8];   // 98,304 B
  __shared__ float hloc[16][CC + 1];
  __shared__ float zbuf[16][CC + 1];
  __shared__ unsigned short un[16][40];
  __shared__ unsigned short hnew[16][40];

  // ---- stage Wh fp32 -> bf16 K-major LDS ----
  {
    const float* wsrc[3] = { Whz + (size_t)layer * 262144,
                             Whr + (size_t)layer * 262144,
                             Whg + (size_t)layer * 262144 };
    for (int idx = tid; idx < 12288; idx += 128) {
      int gate = idx >> 12;            // 0..2
      int r = idx & 4095;
      int c = r >> 7, k4 = r & 127;
      float4 v = *(const float4*)(wsrc[gate] + (size_t)(cbase + c) * 512 + k4 * 4);
      int o = k4 >> 1, base = (k4 & 1) * 4;
      Whs[gate][o][c][base + 0] = f2bf(v.x);
      Whs[gate][o][c][base + 1] = f2bf(v.y);
      Whs[gate][o][c][base + 2] = f2bf(v.z);
      Whs[gate][o][c][base + 3] = f2bf(v.w);
    }
  }
  // ---- init local h slice (fp32) -- no broadcast needed at tl==0 ----
  for (int q = tid; q < 16 * CC; q += 128) {
    int row = q >> 5, c = q & 31;
    int b = g * 16 + row;
    hloc[row][c] = (tstart == 0)
                     ? h0[(size_t)b * 1536 + layer * 512 + cbase + c]
                     : hstate[(size_t)b * 512 + cbase + c];
  }
  __syncthreads();

  const int l15 = lane & 15;
  const int kq  = lane >> 4;

  float bzc[2], brc[2], bgc[2];
#pragma unroll
  for (int T = 0; T < 2; T++) {
    bzc[T] = bz[(size_t)layer * 512 + cbase + T * 16 + l15];
    brc[T] = br[(size_t)layer * 512 + cbase + T * 16 + l15];
    bgc[T] = bg[(size_t)layer * 512 + cbase + T * 16 + l15];
  }

  for (int tl = 0; tl < CT; tl++) {
    if (wave == 0) {
      // ---- prefetch P (cached, independent of h) ----
      float pr[2][4], pz[2][4];
#pragma unroll
      for (int T = 0; T < 2; T++)
#pragma unroll
        for (int rg = 0; rg < 4; rg++) {
          size_t off = (size_t)tl * 32768 + (size_t)(g * 16 + kq * 4 + rg) * 512 + cbase + T * 16 + l15;
          pr[T][rg] = bf2f(Pr[off]);
          pz[T][rg] = bf2f(Pz[off]);
        }
      // ---- acquire h(t-1) fragments ----
      int4 hf[16];
      if (tl == 0) {
        const float* hs = (tstart == 0)
                            ? h0 + (size_t)(g * 16 + l15) * 1536 + (size_t)layer * 512
                            : hstate + (size_t)(g * 16 + l15) * 512;
#pragma unroll
        for (int kc = 0; kc < 16; kc++) {
          int c0 = kq * 8 + kc * 32;
          float4 v0 = *(const float4*)(hs + c0);
          float4 v1 = *(const float4*)(hs + c0 + 4);
          int w0 = (int)f2bf(v0.x) | ((int)f2bf(v0.y) << 16);
          int w1 = (int)f2bf(v0.z) | ((int)f2bf(v0.w) << 16);
          int w2 = (int)f2bf(v1.x) | ((int)f2bf(v1.y) << 16);
          int w3 = (int)f2bf(v1.z) | ((int)f2bf(v1.w) << 16);
          hf[kc] = int4{w0, w1, w2, w3};
        }
      } else {
        poll_slab16(Hbuf + (size_t)(tstart + tl - 1) * 32768 + (g * 16 + l15) * 512 + kq * 8, hf);
      }
      // ---- r gate first (feeds the u-hop) ----
      f32x4 ar[2] = { f32x4{0.f,0.f,0.f,0.f}, f32x4{0.f,0.f,0.f,0.f} };
#pragma unroll
      for (int kc = 0; kc < 16; kc++)
#pragma unroll
        for (int T = 0; T < 2; T++)
          ar[T] = mfma16(hf[kc], *(const int4*)&Whs[1][kc * 4 + kq][T * 16 + l15][0], ar[T]);
#pragma unroll
      for (int T = 0; T < 2; T++)
#pragma unroll
        for (int rg = 0; rg < 4; rg++) {
          int row = kq * 4 + rg, c = T * 16 + l15;
          float rv = sig_(ar[T][rg] + pr[T][rg] + brc[T]);
          un[row][c] = f2bf(rv * hloc[row][c]);
        }
      // coalesced u publish; value IS the flag
      {
        int4 v = *(const int4*)&un[lane >> 2][(lane & 3) * 8];
        st_wt128(Ubuf + (size_t)tl * 32768 + (g * 16 + (lane >> 2)) * 512 + cbase + (lane & 3) * 8, v);
      }
      // ---- z gate (off the u critical path; store drains in background) ----
      f32x4 az[2] = { f32x4{0.f,0.f,0.f,0.f}, f32x4{0.f,0.f,0.f,0.f} };
#pragma unroll
      for (int kc = 0; kc < 16; kc++)
#pragma unroll
        for (int T = 0; T < 2; T++)
          az[T] = mfma16(hf[kc], *(const int4*)&Whs[0][kc * 4 + kq][T * 16 + l15][0], az[T]);
#pragma unroll
      for (int T = 0; T < 2; T++)
#pragma unroll
        for (int rg = 0; rg < 4; rg++)
          zbuf[kq * 4 + rg][T * 16 + l15] = sig_(az[T][rg] + pz[T][rg] + bzc[T]);
    } else {
      // ---- prefetch Pg ----
      float pg[2][4];
#pragma unroll
      for (int T = 0; T < 2; T++)
#pragma unroll
        for (int rg = 0; rg < 4; rg++)
          pg[T][rg] = bf2f(Pg[(size_t)tl * 32768 + (size_t)(g * 16 + kq * 4 + rg) * 512 + cbase + T * 16 + l15]);
      // ---- acquire u(t): data-as-flag poll ----
      int4 uf[16];
      poll_slab16(Ubuf + (size_t)tl * 32768 + (g * 16 + l15) * 512 + kq * 8, uf);
      f32x4 ag[2] = { f32x4{0.f,0.f,0.f,0.f}, f32x4{0.f,0.f,0.f,0.f} };
#pragma unroll
      for (int kc = 0; kc < 16; kc++)
#pragma unroll
        for (int T = 0; T < 2; T++)
          ag[T] = mfma16(uf[kc], *(const int4*)&Whs[2][kc * 4 + kq][T * 16 + l15][0], ag[T]);
#pragma unroll
      for (int T = 0; T < 2; T++)
#pragma unroll
        for (int rg = 0; rg < 4; rg++)
          ag[T][rg] += pg[T][rg] + bgc[T];
      __syncthreads();   // A: zbuf ready (wave0 wrote it pre-barrier)
#pragma unroll
      for (int T = 0; T < 2; T++)
#pragma unroll
        for (int rg = 0; rg < 4; rg++) {
          int row = kq * 4 + rg, c = T * 16 + l15;
          float gv = tanh_(ag[T][rg]);
          float z  = zbuf[row][c];
          float h  = hloc[row][c];
          float hn = z * h + (1.0f - z) * gv;
          hloc[row][c] = hn;
          hnew[row][c] = f2bf(hn);
        }
      // coalesced h publish; value IS the flag
      {
        int4 v = *(const int4*)&hnew[lane >> 2][(lane & 3) * 8];
        st_wt128(&Hbuf[(size_t)(tstart + tl) * 32768 + (g * 16 + (lane >> 2)) * 512 + cbase + (lane & 3) * 8], v);
      }
    }
    if (wave == 0) __syncthreads();  // A (wave0 side)
    __syncthreads();                 // B: hloc/zbuf safe for next step
  }

  // ---- chunk carry-out ----
  for (int q = tid; q < 16 * CC; q += 128) {
    int row = q >> 5, c = q & 31;
    int b = g * 16 + row;
    float v = hloc[row][c];
    hstate[(size_t)b * 512 + cbase + c] = v;
    if (tstart + CT == 1024)
      hidout[(size_t)b * 1536 + layer * 512 + cbase + c] = v;
  }
}

// ---------------------------------------------------------------------------
// launcher
// ---------------------------------------------------------------------------
extern "C" void kernel_launch(void* const* d_in, const int* in_sizes, int n_in,
                              void* d_out, int out_size, void* d_ws, size_t ws_size,
                              hipStream_t stream) {
  const float* X    = (const float*)d_in[0];
  const float* H0   = (const float*)d_in[1];
  const float* Wx0z = (const float*)d_in[2];
  const float* Wx0r = (const float*)d_in[3];
  const float* Wx0g = (const float*)d_in[4];
  const float* Wxz  = (const float*)d_in[5];
  const float* Wxr  = (const float*)d_in[6];
  const float* Wxg  = (const float*)d_in[7];
  const float* Whz  = (const float*)d_in[8];
  const float* Whr  = (const float*)d_in[9];
  const float* Whg  = (const float*)d_in[10];
  const float* bz   = (const float*)d_in[11];
  const float* br   = (const float*)d_in[12];
  const float* bg   = (const float*)d_in[13];
  const float* Wy   = (const float*)d_in[14];
  const float* by   = (const float*)d_in[15];

  // ---- workspace tiering ----
  // need(n) = 87,949,312 + n*67,108,864  (n=1 uses single hstate: 154,796,032
  // == round-8's proven byte range exactly)
  int nslot = 1;
  if (ws_size >= 289275904ull)      nslot = 3;
  else if (ws_size >= 222167040ull) nslot = 2;

  char* w = (char*)d_ws;
  unsigned short* Xt    = (unsigned short*)(w + 0);          // 16,777,216
  unsigned short* Wx0zb = (unsigned short*)(w + 16777216);
  unsigned short* Wx0rb = (unsigned short*)(w + 16908288);
  unsigned short* Wx0gb = (unsigned short*)(w + 17039360);
  unsigned short* Wxzb  = (unsigned short*)(w + 17170432);
  unsigned short* Wxrb  = (unsigned short*)(w + 18219008);
  unsigned short* Wxgb  = (unsigned short*)(w + 19267584);
  unsigned short* Wyb   = (unsigned short*)(w + 20316160);
  size_t off = 20447232;                 // start of slot-strided P region
  const size_t PBLK = 50331648;          // 3 gates x 16,777,216 per slot
  unsigned short* PzB = (unsigned short*)(w + off);
  unsigned short* PrB = (unsigned short*)(w + off + 16777216);
  unsigned short* PgB = (unsigned short*)(w + off + 33554432);
  size_t hbOff  = off + (size_t)nslot * PBLK;
  unsigned short* Hb  = (unsigned short*)(w + hbOff);        // 67,108,864
  size_t hstOff = hbOff + 67108864;
  float* hst          = (float*)(w + hstOff);                // 1 or 3 x 131,072
  size_t uOff   = hstOff + (size_t)(nslot >= 2 ? 3 : 1) * 131072;
  unsigned short* UbB = (unsigned short*)(w + uOff);         // nslot x 16,777,216
  int hstStride = (nslot >= 2) ? 32768 : 0;

  auto cvt = [&](const float* s, unsigned short* d, int n) {
    int n4 = n / 4;
    cvt_bf16<<<dim3((n4 + 255) / 256), dim3(256), 0, stream>>>(s, d, n4);
  };
  xt_k<<<dim3(8192), dim3(256), 0, stream>>>(X, Xt);
  cvt(Wx0z, Wx0zb, 65536);
  cvt(Wx0r, Wx0rb, 65536);
  cvt(Wx0g, Wx0gb, 65536);
  cvt(Wxz, Wxzb, 524288);
  cvt(Wxr, Wxrb, 524288);
  cvt(Wxg, Wxgb, 524288);
  cvt(Wy, Wyb, 65536);

  float* hidout = (float*)d_out + 8388608;

  // ---- wavefront schedule over cells (cell id = layer*4 + chunk) ----
  // deps: (l,c) <- (l,c-1) [hstate], (l-1,c) [Hb via GEMM, same dispatch]
  static const signed char sched3[6][3]  = {
      {0,-1,-1},{1,4,-1},{2,5,8},{3,6,9},{7,10,-1},{11,-1,-1}};
  static const signed char sched2[7][3]  = {
      {0,-1,-1},{1,4,-1},{2,5,-1},{3,8,-1},{6,9,-1},{7,10,-1},{11,-1,-1}};
  static const signed char sched1[12][3] = {
      {0,-1,-1},{1,-1,-1},{2,-1,-1},{3,-1,-1},{4,-1,-1},{5,-1,-1},
      {6,-1,-1},{7,-1,-1},{8,-1,-1},{9,-1,-1},{10,-1,-1},{11,-1,-1}};
  const signed char (*sched)[3] = sched1;
  int ndisp = 12;
  if (nslot == 3)      { sched = sched3; ndisp = 6; }
  else if (nslot == 2) { sched = sched2; ndisp = 7; }

  for (int d = 0; d < ndisp; d++) {
    RecMeta meta{};
    meta.hstStride = hstStride;
    int nc = 0;
    // phase 1: GEMMs (read prev-layer Hb chunks, write per-slot P)
    for (int s = 0; s < 3; s++) {
      int cid = sched[d][s];
      if (cid < 0) break;
      int layer = cid >> 2, chunk = cid & 3, tstart = chunk * CT;
      const unsigned short *Ap, *wz, *wr_, *wg;
      int K;
      if (layer == 0) {
        Ap = Xt + (size_t)tstart * 64 * 128;
        wz = Wx0zb; wr_ = Wx0rb; wg = Wx0gb; K = 128;
      } else {
        Ap = Hb + (size_t)tstart * 64 * 512;
        wz = Wxzb + (size_t)(layer - 1) * 262144;
        wr_ = Wxrb + (size_t)(layer - 1) * 262144;
        wg = Wxgb + (size_t)(layer - 1) * 262144;
        K = 512;
      }
      unsigned short* Pz = PzB + (size_t)nc * PSLOT_SHORTS;
      unsigned short* Pr = PrB + (size_t)nc * PSLOT_SHORTS;
      unsigned short* Pg = PgB + (size_t)nc * PSLOT_SHORTS;
      gemm_bt<<<dim3(128, 4), 256, 0, stream>>>(Ap, wz,  Pz, (const float*)nullptr, 16384, 512, K, 0);
      gemm_bt<<<dim3(128, 4), 256, 0, stream>>>(Ap, wr_, Pr, (const float*)nullptr, 16384, 512, K, 0);
      gemm_bt<<<dim3(128, 4), 256, 0, stream>>>(Ap, wg,  Pg, (const float*)nullptr, 16384, 512, K, 0);
      meta.l[nc] = layer; meta.ts[nc] = tstart; meta.slot[nc] = nc;
      nc++;
    }
    // phase 2: poison the Hb chunks this dispatch's cells will write + U slots
    for (int s = 0; s < nc; s++) {
      poison_k<<<dim3(2048), dim3(256), 0, stream>>>(
          (unsigned long long*)(Hb + (size_t)meta.ts[s] * 32768),
          (unsigned long long*)(UbB + (size_t)meta.slot[s] * USLOT_SHORTS));
    }
    // phase 3: concurrent independent recurrence cells
    gru_rec<<<dim3(nc * 64), dim3(128), 0, stream>>>(
        Whz, Whr, Whg, bz, br, bg, PzB, PrB, PgB, H0, hst, Hb, UbB,
        hidout, meta);
  }

  // Y = H2 @ Wy^T + by  -> (B,S,O) fp32
  gemm_bt<<<dim3(512, 1), 256, 0, stream>>>(Hb, Wyb, d_out, by, 65536, 128, 512, 2);
}

// Round 4
// 10883.537 us; speedup vs baseline: 2.1304x; 1.3083x over previous
//
#include <hip/hip_runtime.h>

// ---------------------------------------------------------------------------
// MultilayerGRU  B=64 S=1024 I=128 H=512 L=3 O=128
// Round 11: deeper wavefront (C=8 chunks) + fused 3-gate GEMM.
// Round-10 evidence: wavefront works (14.24 ms), width-3 diagonals cost only
// +3% vs serial -> no MALL contention between concurrent cells. Per-step time
// is a fabric constant (~7.4 us, protocol-independent, rounds 7/8). So the
// remaining levers are schedule-level:
//   (1) more chunks: T_rec ~ (C+L-1)/C * S * 7.4us -> C=8 gives 10 diagonals
//       x 128 steps = 9.5 ms vs 11.4 ms at C=4. Width still <= L=3.
//   (2) gemm3: one dispatch computes all three gate pre-activations (shared
//       A-tile, blockIdx.y in [0,12) = gate x n-block): 3x fewer GEMM
//       dispatches and 3x fewer A reads.
// Cell internals byte-identical to round 10 (data-as-flag NaN-poison polling,
// zero fences). Slot strides are single-source macros used by BOTH launcher
// and kernel (round-9 bug class excluded). hstate is per-layer (3 copies) in
// all tiers. Workspace: 3-slot 188.6 MB (fits proven >=289 MB), serial
// 1-slot 121.5 MB fallback.
// ---------------------------------------------------------------------------

typedef float f32x4 __attribute__((ext_vector_type(4)));
typedef __bf16 bf16x8 __attribute__((ext_vector_type(8)));

#define CT 128   // timesteps per chunk (C = 8 chunks)
#define NCHUNK 8
#define CC 32    // H-columns per workgroup slice
#define POIS 0x7FC07FC0
// Per-slot P block: 3 gates x CT*B*H bf16 = 3 x 8,388,608 B = 25,165,824 B
#define PSLOT_SHORTS 12582912ull
#define PGATE_BYTES  8388608ull
// Per-slot U block: CT*B*H bf16 = 8,388,608 B
#define USLOT_SHORTS 4194304ull

struct RecMeta {
  int l[3];     // layer per cell
  int ts[3];    // tstart per cell
  int slot[3];  // P/U slot per cell
};

__device__ __forceinline__ unsigned short f2bf(float x) {
  unsigned int u = __builtin_bit_cast(unsigned int, x);
  u += 0x7fffu + ((u >> 16) & 1u);   // round-to-nearest-even
  return (unsigned short)(u >> 16);
}
__device__ __forceinline__ float bf2f(unsigned short h) {
  unsigned int u = ((unsigned int)h) << 16;
  return __builtin_bit_cast(float, u);
}
__device__ __forceinline__ f32x4 mfma16(int4 a, int4 b, f32x4 c) {
  return __builtin_amdgcn_mfma_f32_16x16x32_bf16(
      __builtin_bit_cast(bf16x8, a), __builtin_bit_cast(bf16x8, b), c, 0, 0, 0);
}
__device__ __forceinline__ float sig_(float x) { return 1.0f / (1.0f + __expf(-x)); }
__device__ __forceinline__ float tanh_(float x) {
  float ax = fabsf(x);
  float e  = __expf(2.0f * ax);
  float t  = 1.0f - 2.0f / (e + 1.0f);
  return x < 0.0f ? -t : t;
}

// ---- coherence-point (cross-XCD) access helpers ----
__device__ __forceinline__ void issue_ld16(const unsigned short* p, int4& d) {
  asm volatile("global_load_dwordx4 %0, %1, off sc0 sc1"
               : "=v"(d) : "v"(p) : "memory");
}
__device__ __forceinline__ void st_wt128(unsigned short* p, int4 v) {
  unsigned long long lo = ((unsigned long long)(unsigned int)v.y << 32) | (unsigned int)v.x;
  unsigned long long hi = ((unsigned long long)(unsigned int)v.w << 32) | (unsigned int)v.z;
  __hip_atomic_store((unsigned long long*)p,     lo, __ATOMIC_RELAXED, __HIP_MEMORY_SCOPE_AGENT);
  __hip_atomic_store((unsigned long long*)p + 1, hi, __ATOMIC_RELAXED, __HIP_MEMORY_SCOPE_AGENT);
}
__device__ __forceinline__ void wait_vm0() {
  asm volatile("s_waitcnt vmcnt(0)" ::: "memory");
}

// Poll a 16-row x 512-col bf16 slab until no dword is poison. Data is valid
// in d[] on return: per-dword store atomicity, the value IS the signal.
__device__ __forceinline__ void poll_slab16(const unsigned short* p, int4* d) {
  for (;;) {
#pragma unroll
    for (int kc = 0; kc < 16; kc++) issue_ld16(p + kc * 32, d[kc]);
    wait_vm0();
    int bad = 0;
#pragma unroll
    for (int kc = 0; kc < 16; kc++)
      bad |= (d[kc].x == POIS) | (d[kc].y == POIS) | (d[kc].z == POIS) | (d[kc].w == POIS);
    if (!__any(bad)) return;
  }
}

// ---------------------------------------------------------------------------
__global__ void cvt_bf16(const float* __restrict__ src, unsigned short* __restrict__ dst, int n4) {
  int i = blockIdx.x * blockDim.x + threadIdx.x;
  if (i < n4) {
    float4 v = *(const float4*)(src + (size_t)i * 4);
    ushort4 o;
    o.x = f2bf(v.x); o.y = f2bf(v.y); o.z = f2bf(v.z); o.w = f2bf(v.w);
    *(ushort4*)(dst + (size_t)i * 4) = o;
  }
}

// X (64,1024,128) f32 -> Xt row (t*64+b), 128 bf16
__global__ void xt_k(const float* __restrict__ X, unsigned short* __restrict__ Xt) {
  int idx = blockIdx.x * 256 + threadIdx.x;
  int i4 = idx & 31, rest = idx >> 5;
  int t = rest & 1023, b = rest >> 10;
  float4 v = *(const float4*)(X + (size_t)(b * 1024 + t) * 128 + i4 * 4);
  ushort4 o;
  o.x = f2bf(v.x); o.y = f2bf(v.y); o.z = f2bf(v.z); o.w = f2bf(v.w);
  *(ushort4*)(Xt + (size_t)(t * 64 + b) * 128 + i4 * 4) = o;
}

// Pre-poison one Hb chunk (a) and one Ubuf slot (b): 8,388,608 B each =
// 1,048,576 u64 each. Grid 1024 x 256, 4 u64 per thread per region.
// Agent-scope stores so poison is at the coherence point the polls read.
__global__ void poison_k(unsigned long long* __restrict__ a,
                         unsigned long long* __restrict__ b) {
  const unsigned long long P = 0x7FC07FC07FC07FC0ull;
  unsigned long long* pa = a + (size_t)blockIdx.x * 1024 + threadIdx.x;
  unsigned long long* pb = b + (size_t)blockIdx.x * 1024 + threadIdx.x;
#pragma unroll
  for (int k = 0; k < 4; k++) {
    __hip_atomic_store(pa + k * 256, P, __ATOMIC_RELAXED, __HIP_MEMORY_SCOPE_AGENT);
    __hip_atomic_store(pb + k * 256, P, __ATOMIC_RELAXED, __HIP_MEMORY_SCOPE_AGENT);
  }
}

// ---------------------------------------------------------------------------
// gemm3: all three gate pre-activations in one dispatch (shared A).
// P{z,r,g}[M,512] = A[M,K] @ W{z,r,g}[512,K]^T, bf16 out.
// blockIdx.y in [0,12): gate = y>>2, n0 = (y&3)*128.
// ---------------------------------------------------------------------------
__global__ __launch_bounds__(256)
void gemm3(const unsigned short* __restrict__ A,
           const unsigned short* __restrict__ Wz, const unsigned short* __restrict__ Wr,
           const unsigned short* __restrict__ Wg,
           unsigned short* __restrict__ Pz, unsigned short* __restrict__ Pr,
           unsigned short* __restrict__ Pg,
           int M, int K) {
  __shared__ unsigned short As[128][72];
  __shared__ unsigned short Bs[128][72];
  const int gate = blockIdx.y >> 2;
  const unsigned short* W = (gate == 0) ? Wz : (gate == 1) ? Wr : Wg;
  unsigned short* C       = (gate == 0) ? Pz : (gate == 1) ? Pr : Pg;
  const int tid  = threadIdx.x;
  const int lane = tid & 63;
  const int wave = tid >> 6;
  const int wr = wave >> 1, wc = wave & 1;
  const int m0 = blockIdx.x * 128, n0 = (blockIdx.y & 3) * 128;

  f32x4 acc[4][4];
  for (int i = 0; i < 4; i++)
    for (int j = 0; j < 4; j++) acc[i][j] = f32x4{0.f, 0.f, 0.f, 0.f};

  for (int k0 = 0; k0 < K; k0 += 64) {
    int4 va[4], vb[4];
#pragma unroll
    for (int it = 0; it < 4; it++) {
      int q = tid + it * 256;
      int r = q >> 3, kc = q & 7;
      va[it] = *(const int4*)(A + (size_t)(m0 + r) * K + k0 + kc * 8);
      vb[it] = *(const int4*)(W + (size_t)(n0 + r) * K + k0 + kc * 8);
    }
    __syncthreads();
#pragma unroll
    for (int it = 0; it < 4; it++) {
      int q = tid + it * 256;
      int r = q >> 3, kc = q & 7;
      *(int4*)&As[r][kc * 8] = va[it];
      *(int4*)&Bs[r][kc * 8] = vb[it];
    }
    __syncthreads();
#pragma unroll
    for (int kc = 0; kc < 2; kc++) {
      int koff = kc * 32 + (lane >> 4) * 8;
      int4 af[4], bfr[4];
#pragma unroll
      for (int mt = 0; mt < 4; mt++) af[mt]  = *(const int4*)&As[wr * 64 + mt * 16 + (lane & 15)][koff];
#pragma unroll
      for (int nt = 0; nt < 4; nt++) bfr[nt] = *(const int4*)&Bs[wc * 64 + nt * 16 + (lane & 15)][koff];
#pragma unroll
      for (int mt = 0; mt < 4; mt++)
#pragma unroll
        for (int nt = 0; nt < 4; nt++)
          acc[mt][nt] = mfma16(af[mt], bfr[nt], acc[mt][nt]);
    }
  }

#pragma unroll
  for (int mt = 0; mt < 4; mt++)
#pragma unroll
    for (int nt = 0; nt < 4; nt++)
#pragma unroll
      for (int rg = 0; rg < 4; rg++) {
        int m = m0 + wr * 64 + mt * 16 + (lane >> 4) * 4 + rg;
        int n = n0 + wc * 64 + nt * 16 + (lane & 15);
        C[(size_t)m * 512 + n] = f2bf(acc[mt][nt][rg]);
      }
}

// ---------------------------------------------------------------------------
// C[M,N] = A[M,K] @ W[N,K]^T, fp32 out + bias, row remap m=(t*64+b) -> out
// row b*1024+t. Used for the final Y projection only.   (proven)
// ---------------------------------------------------------------------------
__global__ __launch_bounds__(256)
void gemm_bt(const unsigned short* __restrict__ A, const unsigned short* __restrict__ W,
             float* __restrict__ Cout, const float* __restrict__ bias,
             int M, int N, int K) {
  __shared__ unsigned short As[128][72];
  __shared__ unsigned short Bs[128][72];
  const int tid  = threadIdx.x;
  const int lane = tid & 63;
  const int wave = tid >> 6;
  const int wr = wave >> 1, wc = wave & 1;
  const int m0 = blockIdx.x * 128, n0 = blockIdx.y * 128;

  f32x4 acc[4][4];
  for (int i = 0; i < 4; i++)
    for (int j = 0; j < 4; j++) acc[i][j] = f32x4{0.f, 0.f, 0.f, 0.f};

  for (int k0 = 0; k0 < K; k0 += 64) {
    int4 va[4], vb[4];
#pragma unroll
    for (int it = 0; it < 4; it++) {
      int q = tid + it * 256;
      int r = q >> 3, kc = q & 7;
      va[it] = *(const int4*)(A + (size_t)(m0 + r) * K + k0 + kc * 8);
      vb[it] = *(const int4*)(W + (size_t)(n0 + r) * K + k0 + kc * 8);
    }
    __syncthreads();
#pragma unroll
    for (int it = 0; it < 4; it++) {
      int q = tid + it * 256;
      int r = q >> 3, kc = q & 7;
      *(int4*)&As[r][kc * 8] = va[it];
      *(int4*)&Bs[r][kc * 8] = vb[it];
    }
    __syncthreads();
#pragma unroll
    for (int kc = 0; kc < 2; kc++) {
      int koff = kc * 32 + (lane >> 4) * 8;
      int4 af[4], bfr[4];
#pragma unroll
      for (int mt = 0; mt < 4; mt++) af[mt]  = *(const int4*)&As[wr * 64 + mt * 16 + (lane & 15)][koff];
#pragma unroll
      for (int nt = 0; nt < 4; nt++) bfr[nt] = *(const int4*)&Bs[wc * 64 + nt * 16 + (lane & 15)][koff];
#pragma unroll
      for (int mt = 0; mt < 4; mt++)
#pragma unroll
        for (int nt = 0; nt < 4; nt++)
          acc[mt][nt] = mfma16(af[mt], bfr[nt], acc[mt][nt]);
    }
  }

#pragma unroll
  for (int mt = 0; mt < 4; mt++)
#pragma unroll
    for (int nt = 0; nt < 4; nt++)
#pragma unroll
      for (int rg = 0; rg < 4; rg++) {
        int m = m0 + wr * 64 + mt * 16 + (lane >> 4) * 4 + rg;
        int n = n0 + wc * 64 + nt * 16 + (lane & 15);
        Cout[(size_t)((m & 63) * 1024 + (m >> 6)) * N + n] = acc[mt][nt][rg] + bias[n];
      }
}

// ---------------------------------------------------------------------------
// Recurrence: up to 3 independent (layer,chunk) cells per dispatch.
// Cell = blockIdx.x>>6 (64 WGs each = 4 batch-groups x 16 col-slices).
// Cell internals identical to round 10 (data-as-flag, NaN-poison polling).
// ---------------------------------------------------------------------------
__global__ __launch_bounds__(128)
void gru_rec(const float* __restrict__ Whz, const float* __restrict__ Whr,
             const float* __restrict__ Whg,
             const float* __restrict__ bz, const float* __restrict__ br,
             const float* __restrict__ bg,
             const unsigned short* __restrict__ PzB, const unsigned short* __restrict__ PrB,
             const unsigned short* __restrict__ PgB, // slot-strided bases
             const float* __restrict__ h0,           // (B,L,H) fp32 original
             float* __restrict__ hstateB,            // per-layer (B,H) fp32 carries
             unsigned short* __restrict__ Hbuf,      // (S,B,H) bf16, per-t slots (poisoned)
             unsigned short* __restrict__ UbufB,     // slot-strided (CT,B,H) bf16 (poisoned)
             float* __restrict__ hidout,             // (B,L,H) fp32
             RecMeta meta) {
  const int cell = blockIdx.x >> 6;
  const int bid  = blockIdx.x & 63;
  const int layer  = meta.l[cell];
  const int tstart = meta.ts[cell];
  const int slot   = meta.slot[cell];
  const unsigned short* Pz = PzB + (size_t)slot * PSLOT_SHORTS;
  const unsigned short* Pr = PrB + (size_t)slot * PSLOT_SHORTS;
  const unsigned short* Pg = PgB + (size_t)slot * PSLOT_SHORTS;
  unsigned short* Ubuf     = UbufB + (size_t)slot * USLOT_SHORTS;
  float* hstate            = hstateB + (size_t)layer * 32768;

  const int g    = bid & 3;          // batch group (16 rows)
  const int mem  = bid >> 2;         // col slice 0..15
  const int cbase = mem * CC;
  const int tid  = threadIdx.x;
  const int lane = tid & 63;
  const int wave = tid >> 6;         // 0..1

  // K-major weight LDS: [gate 0=z,1=r,2=g][K-octet 0..63][col 0..31][8 bf16]
  __shared__ unsigned short Whs[3][64][32][8];   // 98,304 B
  __shared__ float hloc[16][CC + 1];
  __shared__ float zbuf[16][CC + 1];
  __shared__ unsigned short un[16][40];
  __shared__ unsigned short hnew[16][40];

  // ---- stage Wh fp32 -> bf16 K-major LDS ----
  {
    const float* wsrc[3] = { Whz + (size_t)layer * 262144,
                             Whr + (size_t)layer * 262144,
                             Whg + (size_t)layer * 262144 };
    for (int idx = tid; idx < 12288; idx += 128) {
      int gate = idx >> 12;            // 0..2
      int r = idx & 4095;
      int c = r >> 7, k4 = r & 127;
      float4 v = *(const float4*)(wsrc[gate] + (size_t)(cbase + c) * 512 + k4 * 4);
      int o = k4 >> 1, base = (k4 & 1) * 4;
      Whs[gate][o][c][base + 0] = f2bf(v.x);
      Whs[gate][o][c][base + 1] = f2bf(v.y);
      Whs[gate][o][c][base + 2] = f2bf(v.z);
      Whs[gate][o][c][base + 3] = f2bf(v.w);
    }
  }
  // ---- init local h slice (fp32) -- no broadcast needed at tl==0 ----
  for (int q = tid; q < 16 * CC; q += 128) {
    int row = q >> 5, c = q & 31;
    int b = g * 16 + row;
    hloc[row][c] = (tstart == 0)
                     ? h0[(size_t)b * 1536 + layer * 512 + cbase + c]
                     : hstate[(size_t)b * 512 + cbase + c];
  }
  __syncthreads();

  const int l15 = lane & 15;
  const int kq  = lane >> 4;

  float bzc[2], brc[2], bgc[2];
#pragma unroll
  for (int T = 0; T < 2; T++) {
    bzc[T] = bz[(size_t)layer * 512 + cbase + T * 16 + l15];
    brc[T] = br[(size_t)layer * 512 + cbase + T * 16 + l15];
    bgc[T] = bg[(size_t)layer * 512 + cbase + T * 16 + l15];
  }

  for (int tl = 0; tl < CT; tl++) {
    if (wave == 0) {
      // ---- prefetch P (cached, independent of h) ----
      float pr[2][4], pz[2][4];
#pragma unroll
      for (int T = 0; T < 2; T++)
#pragma unroll
        for (int rg = 0; rg < 4; rg++) {
          size_t off = (size_t)tl * 32768 + (size_t)(g * 16 + kq * 4 + rg) * 512 + cbase + T * 16 + l15;
          pr[T][rg] = bf2f(Pr[off]);
          pz[T][rg] = bf2f(Pz[off]);
        }
      // ---- acquire h(t-1) fragments ----
      int4 hf[16];
      if (tl == 0) {
        const float* hs = (tstart == 0)
                            ? h0 + (size_t)(g * 16 + l15) * 1536 + (size_t)layer * 512
                            : hstate + (size_t)(g * 16 + l15) * 512;
#pragma unroll
        for (int kc = 0; kc < 16; kc++) {
          int c0 = kq * 8 + kc * 32;
          float4 v0 = *(const float4*)(hs + c0);
          float4 v1 = *(const float4*)(hs + c0 + 4);
          int w0 = (int)f2bf(v0.x) | ((int)f2bf(v0.y) << 16);
          int w1 = (int)f2bf(v0.z) | ((int)f2bf(v0.w) << 16);
          int w2 = (int)f2bf(v1.x) | ((int)f2bf(v1.y) << 16);
          int w3 = (int)f2bf(v1.z) | ((int)f2bf(v1.w) << 16);
          hf[kc] = int4{w0, w1, w2, w3};
        }
      } else {
        poll_slab16(Hbuf + (size_t)(tstart + tl - 1) * 32768 + (g * 16 + l15) * 512 + kq * 8, hf);
      }
      // ---- r gate first (feeds the u-hop) ----
      f32x4 ar[2] = { f32x4{0.f,0.f,0.f,0.f}, f32x4{0.f,0.f,0.f,0.f} };
#pragma unroll
      for (int kc = 0; kc < 16; kc++)
#pragma unroll
        for (int T = 0; T < 2; T++)
          ar[T] = mfma16(hf[kc], *(const int4*)&Whs[1][kc * 4 + kq][T * 16 + l15][0], ar[T]);
#pragma unroll
      for (int T = 0; T < 2; T++)
#pragma unroll
        for (int rg = 0; rg < 4; rg++) {
          int row = kq * 4 + rg, c = T * 16 + l15;
          float rv = sig_(ar[T][rg] + pr[T][rg] + brc[T]);
          un[row][c] = f2bf(rv * hloc[row][c]);
        }
      // coalesced u publish; value IS the flag
      {
        int4 v = *(const int4*)&un[lane >> 2][(lane & 3) * 8];
        st_wt128(Ubuf + (size_t)tl * 32768 + (g * 16 + (lane >> 2)) * 512 + cbase + (lane & 3) * 8, v);
      }
      // ---- z gate (off the u critical path; store drains in background) ----
      f32x4 az[2] = { f32x4{0.f,0.f,0.f,0.f}, f32x4{0.f,0.f,0.f,0.f} };
#pragma unroll
      for (int kc = 0; kc < 16; kc++)
#pragma unroll
        for (int T = 0; T < 2; T++)
          az[T] = mfma16(hf[kc], *(const int4*)&Whs[0][kc * 4 + kq][T * 16 + l15][0], az[T]);
#pragma unroll
      for (int T = 0; T < 2; T++)
#pragma unroll
        for (int rg = 0; rg < 4; rg++)
          zbuf[kq * 4 + rg][T * 16 + l15] = sig_(az[T][rg] + pz[T][rg] + bzc[T]);
    } else {
      // ---- prefetch Pg ----
      float pg[2][4];
#pragma unroll
      for (int T = 0; T < 2; T++)
#pragma unroll
        for (int rg = 0; rg < 4; rg++)
          pg[T][rg] = bf2f(Pg[(size_t)tl * 32768 + (size_t)(g * 16 + kq * 4 + rg) * 512 + cbase + T * 16 + l15]);
      // ---- acquire u(t): data-as-flag poll ----
      int4 uf[16];
      poll_slab16(Ubuf + (size_t)tl * 32768 + (g * 16 + l15) * 512 + kq * 8, uf);
      f32x4 ag[2] = { f32x4{0.f,0.f,0.f,0.f}, f32x4{0.f,0.f,0.f,0.f} };
#pragma unroll
      for (int kc = 0; kc < 16; kc++)
#pragma unroll
        for (int T = 0; T < 2; T++)
          ag[T] = mfma16(uf[kc], *(const int4*)&Whs[2][kc * 4 + kq][T * 16 + l15][0], ag[T]);
#pragma unroll
      for (int T = 0; T < 2; T++)
#pragma unroll
        for (int rg = 0; rg < 4; rg++)
          ag[T][rg] += pg[T][rg] + bgc[T];
      __syncthreads();   // A: zbuf ready (wave0 wrote it pre-barrier)
#pragma unroll
      for (int T = 0; T < 2; T++)
#pragma unroll
        for (int rg = 0; rg < 4; rg++) {
          int row = kq * 4 + rg, c = T * 16 + l15;
          float gv = tanh_(ag[T][rg]);
          float z  = zbuf[row][c];
          float h  = hloc[row][c];
          float hn = z * h + (1.0f - z) * gv;
          hloc[row][c] = hn;
          hnew[row][c] = f2bf(hn);
        }
      // coalesced h publish; value IS the flag
      {
        int4 v = *(const int4*)&hnew[lane >> 2][(lane & 3) * 8];
        st_wt128(&Hbuf[(size_t)(tstart + tl) * 32768 + (g * 16 + (lane >> 2)) * 512 + cbase + (lane & 3) * 8], v);
      }
    }
    if (wave == 0) __syncthreads();  // A (wave0 side)
    __syncthreads();                 // B: hloc/zbuf safe for next step
  }

  // ---- chunk carry-out ----
  for (int q = tid; q < 16 * CC; q += 128) {
    int row = q >> 5, c = q & 31;
    int b = g * 16 + row;
    float v = hloc[row][c];
    hstate[(size_t)b * 512 + cbase + c] = v;
    if (tstart + CT == 1024)
      hidout[(size_t)b * 1536 + layer * 512 + cbase + c] = v;
  }
}

// ---------------------------------------------------------------------------
// launcher
// ---------------------------------------------------------------------------
extern "C" void kernel_launch(void* const* d_in, const int* in_sizes, int n_in,
                              void* d_out, int out_size, void* d_ws, size_t ws_size,
                              hipStream_t stream) {
  const float* X    = (const float*)d_in[0];
  const float* H0   = (const float*)d_in[1];
  const float* Wx0z = (const float*)d_in[2];
  const float* Wx0r = (const float*)d_in[3];
  const float* Wx0g = (const float*)d_in[4];
  const float* Wxz  = (const float*)d_in[5];
  const float* Wxr  = (const float*)d_in[6];
  const float* Wxg  = (const float*)d_in[7];
  const float* Whz  = (const float*)d_in[8];
  const float* Whr  = (const float*)d_in[9];
  const float* Whg  = (const float*)d_in[10];
  const float* bz   = (const float*)d_in[11];
  const float* br   = (const float*)d_in[12];
  const float* bg   = (const float*)d_in[13];
  const float* Wy   = (const float*)d_in[14];
  const float* by   = (const float*)d_in[15];

  // ---- workspace tiering ----
  // need(n) = 20,447,232 (head) + n*25,165,824 (P) + 67,108,864 (Hb)
  //           + 393,216 (hst x3) + n*8,388,608 (U)
  // n=3: 188,612,608   n=1: 121,503,744
  int nslot = (ws_size >= 188612608ull) ? 3 : 1;

  char* w = (char*)d_ws;
  unsigned short* Xt    = (unsigned short*)(w + 0);          // 16,777,216
  unsigned short* Wx0zb = (unsigned short*)(w + 16777216);
  unsigned short* Wx0rb = (unsigned short*)(w + 16908288);
  unsigned short* Wx0gb = (unsigned short*)(w + 17039360);
  unsigned short* Wxzb  = (unsigned short*)(w + 17170432);
  unsigned short* Wxrb  = (unsigned short*)(w + 18219008);
  unsigned short* Wxgb  = (unsigned short*)(w + 19267584);
  unsigned short* Wyb   = (unsigned short*)(w + 20316160);
  const size_t off = 20447232;           // start of slot-strided P region
  unsigned short* PzB = (unsigned short*)(w + off);
  unsigned short* PrB = (unsigned short*)(w + off + PGATE_BYTES);
  unsigned short* PgB = (unsigned short*)(w + off + 2 * PGATE_BYTES);
  size_t hbOff  = off + (size_t)nslot * (PSLOT_SHORTS * 2);
  unsigned short* Hb  = (unsigned short*)(w + hbOff);        // 67,108,864
  size_t hstOff = hbOff + 67108864;
  float* hst          = (float*)(w + hstOff);                // 3 x 131,072
  size_t uOff   = hstOff + 393216;
  unsigned short* UbB = (unsigned short*)(w + uOff);         // nslot x 8,388,608

  auto cvt = [&](const float* s, unsigned short* d, int n) {
    int n4 = n / 4;
    cvt_bf16<<<dim3((n4 + 255) / 256), dim3(256), 0, stream>>>(s, d, n4);
  };
  xt_k<<<dim3(8192), dim3(256), 0, stream>>>(X, Xt);
  cvt(Wx0z, Wx0zb, 65536);
  cvt(Wx0r, Wx0rb, 65536);
  cvt(Wx0g, Wx0gb, 65536);
  cvt(Wxz, Wxzb, 524288);
  cvt(Wxr, Wxrb, 524288);
  cvt(Wxg, Wxgb, 524288);
  cvt(Wy, Wyb, 65536);

  float* hidout = (float*)d_out + 8388608;

  // ---- wavefront schedule, cell id = layer*8 + chunk ----
  // deps: (l,c) <- (l,c-1) [hstate], (l-1,c) [Hb via gemm3, same dispatch grp]
  static const signed char sched3[10][3] = {
      {0,-1,-1},{1,8,-1},{2,9,16},{3,10,17},{4,11,18},
      {5,12,19},{6,13,20},{7,14,21},{15,22,-1},{23,-1,-1}};
  static const signed char sched1[24][3] = {
      {0,-1,-1},{1,-1,-1},{2,-1,-1},{3,-1,-1},{4,-1,-1},{5,-1,-1},
      {6,-1,-1},{7,-1,-1},{8,-1,-1},{9,-1,-1},{10,-1,-1},{11,-1,-1},
      {12,-1,-1},{13,-1,-1},{14,-1,-1},{15,-1,-1},{16,-1,-1},{17,-1,-1},
      {18,-1,-1},{19,-1,-1},{20,-1,-1},{21,-1,-1},{22,-1,-1},{23,-1,-1}};
  const signed char (*sched)[3] = (nslot == 3) ? sched3 : sched1;
  const int ndisp = (nslot == 3) ? 10 : 24;

  for (int d = 0; d < ndisp; d++) {
    RecMeta meta{};
    int nc = 0;
    // phase 1: fused 3-gate GEMMs (read prev-layer Hb, write per-slot P)
    for (int s = 0; s < 3; s++) {
      int cid = sched[d][s];
      if (cid < 0) break;
      int layer = cid >> 3, chunk = cid & 7, tstart = chunk * CT;
      const unsigned short *Ap, *wz, *wr_, *wg;
      int K;
      if (layer == 0) {
        Ap = Xt + (size_t)tstart * 64 * 128;
        wz = Wx0zb; wr_ = Wx0rb; wg = Wx0gb; K = 128;
      } else {
        Ap = Hb + (size_t)tstart * 32768;
        wz = Wxzb + (size_t)(layer - 1) * 262144;
        wr_ = Wxrb + (size_t)(layer - 1) * 262144;
        wg = Wxgb + (size_t)(layer - 1) * 262144;
        K = 512;
      }
      gemm3<<<dim3(CT * 64 / 128, 12), 256, 0, stream>>>(
          Ap, wz, wr_, wg,
          PzB + (size_t)nc * PSLOT_SHORTS,
          PrB + (size_t)nc * PSLOT_SHORTS,
          PgB + (size_t)nc * PSLOT_SHORTS,
          CT * 64, K);
      meta.l[nc] = layer; meta.ts[nc] = tstart; meta.slot[nc] = nc;
      nc++;
    }
    // phase 2: poison the Hb chunks this dispatch's cells will write + U slots
    for (int s = 0; s < nc; s++) {
      poison_k<<<dim3(1024), dim3(256), 0, stream>>>(
          (unsigned long long*)(Hb + (size_t)meta.ts[s] * 32768),
          (unsigned long long*)(UbB + (size_t)meta.slot[s] * USLOT_SHORTS));
    }
    // phase 3: concurrent independent recurrence cells
    gru_rec<<<dim3(nc * 64), dim3(128), 0, stream>>>(
        Whz, Whr, Whg, bz, br, bg, PzB, PrB, PgB, H0, hst, Hb, UbB,
        hidout, meta);
  }

  // Y = H2 @ Wy^T + by  -> (B,S,O) fp32
  gemm_bt<<<dim3(512, 1), 256, 0, stream>>>(Hb, Wyb, (float*)d_out, by, 65536, 128, 512);
}

// Round 8
// 10696.129 us; speedup vs baseline: 2.1678x; 1.0175x over previous
//
#include <hip/hip_runtime.h>

// ---------------------------------------------------------------------------
// MultilayerGRU  B=64 S=1024 I=128 H=512 L=3 O=128
// Round 15: PROVEN POLL RESTORED + deeper wavefront (C=16).
// r12-r14 post-mortem: selective re-poll requires d[kc] live-across-iteration
// with conditional redefinition -> register allocator can spill an
// asm-produced, still-in-flight load destination to scratch (garbage
// snapshot) -> false "clean" -> poison consumed -> NaN. No fence placement
// fixes a producer-side spill. r8-r11's unconditional loop (all d[] redefined
// every iteration, short live ranges) is spill-free and ran 4 rounds clean ->
// restored BYTE-EXACT. Poll-cadence hypothesis also weakly supported (r7
// 1-load poll == r8 16-load poll step time) -> abandoned.
// This round's levers (all schedule-level, proven machinery):
//   - C=16 chunks (CT=64): 18 diagonals, critical path (C+L-1)/C = 1.125x
//     vs 1.25x at C=8. Schedule generated programmatically.
//   - whcvt_k pre-staged Wh image kept (decisive A/B: everything else is
//     r11-proven, so a NaN now indicts whcvt; a pass clears it).
//   - poison3_k: one dispatch poisons all of a diagonal's Hb chunks+U slots
//     (48 -> 18 poison launches).
// Protocol, cell internals, gemm3, workspace style otherwise == r11.
// ---------------------------------------------------------------------------

typedef float f32x4 __attribute__((ext_vector_type(4)));
typedef __bf16 bf16x8 __attribute__((ext_vector_type(8)));

#define CT 64    // timesteps per chunk (C = 16 chunks)
#define NCHUNK 16
#define CC 32    // H-columns per workgroup slice
#define POIS 0x7FC07FC0
// Per-slot P block: 3 gates x CT*B*H bf16 = 3 x 4,194,304 B = 12,582,912 B
#define PGATE_BYTES  4194304ull
#define PSLOT_SHORTS 6291456ull
// Per-slot U block: CT*B*H bf16 = 4,194,304 B
#define USLOT_SHORTS 2097152ull

struct RecMeta {
  int l[3];     // layer per cell
  int ts[3];    // tstart per cell
  int slot[3];  // P/U slot per cell
};

__device__ __forceinline__ unsigned short f2bf(float x) {
  unsigned int u = __builtin_bit_cast(unsigned int, x);
  u += 0x7fffu + ((u >> 16) & 1u);   // round-to-nearest-even
  return (unsigned short)(u >> 16);
}
__device__ __forceinline__ float bf2f(unsigned short h) {
  unsigned int u = ((unsigned int)h) << 16;
  return __builtin_bit_cast(float, u);
}
__device__ __forceinline__ f32x4 mfma16(int4 a, int4 b, f32x4 c) {
  return __builtin_amdgcn_mfma_f32_16x16x32_bf16(
      __builtin_bit_cast(bf16x8, a), __builtin_bit_cast(bf16x8, b), c, 0, 0, 0);
}
__device__ __forceinline__ float sig_(float x) { return 1.0f / (1.0f + __expf(-x)); }
__device__ __forceinline__ float tanh_(float x) {
  float ax = fabsf(x);
  float e  = __expf(2.0f * ax);
  float t  = 1.0f - 2.0f / (e + 1.0f);
  return x < 0.0f ? -t : t;
}

// ---- coherence-point (cross-XCD) access helpers ----
__device__ __forceinline__ void issue_ld16(const unsigned short* p, int4& d) {
  asm volatile("global_load_dwordx4 %0, %1, off sc0 sc1"
               : "=v"(d) : "v"(p) : "memory");
}
__device__ __forceinline__ void st_wt128(unsigned short* p, int4 v) {
  unsigned long long lo = ((unsigned long long)(unsigned int)v.y << 32) | (unsigned int)v.x;
  unsigned long long hi = ((unsigned long long)(unsigned int)v.w << 32) | (unsigned int)v.z;
  __hip_atomic_store((unsigned long long*)p,     lo, __ATOMIC_RELAXED, __HIP_MEMORY_SCOPE_AGENT);
  __hip_atomic_store((unsigned long long*)p + 1, hi, __ATOMIC_RELAXED, __HIP_MEMORY_SCOPE_AGENT);
}
__device__ __forceinline__ void wait_vm0() {
  asm volatile("s_waitcnt vmcnt(0)" ::: "memory");
}

// Poll a 16-row x 512-col bf16 slab until no dword is poison. Data is valid
// in d[] on return: per-dword store atomicity, the value IS the signal.
// BYTE-EXACT r8-r11 loop: all d[] unconditionally redefined every iteration
// (short live ranges -> no spill of in-flight asm destinations).
__device__ __forceinline__ void poll_slab16(const unsigned short* p, int4* d) {
  for (;;) {
#pragma unroll
    for (int kc = 0; kc < 16; kc++) issue_ld16(p + kc * 32, d[kc]);
    wait_vm0();
    int bad = 0;
#pragma unroll
    for (int kc = 0; kc < 16; kc++)
      bad |= (d[kc].x == POIS) | (d[kc].y == POIS) | (d[kc].z == POIS) | (d[kc].w == POIS);
    if (!__any(bad)) return;
  }
}

// ---------------------------------------------------------------------------
__global__ void cvt_bf16(const float* __restrict__ src, unsigned short* __restrict__ dst, int n4) {
  int i = blockIdx.x * blockDim.x + threadIdx.x;
  if (i < n4) {
    float4 v = *(const float4*)(src + (size_t)i * 4);
    ushort4 o;
    o.x = f2bf(v.x); o.y = f2bf(v.y); o.z = f2bf(v.z); o.w = f2bf(v.w);
    *(ushort4*)(dst + (size_t)i * 4) = o;
  }
}

// X (64,1024,128) f32 -> Xt row (t*64+b), 128 bf16
__global__ void xt_k(const float* __restrict__ X, unsigned short* __restrict__ Xt) {
  int idx = blockIdx.x * 256 + threadIdx.x;
  int i4 = idx & 31, rest = idx >> 5;
  int t = rest & 1023, b = rest >> 10;
  float4 v = *(const float4*)(X + (size_t)(b * 1024 + t) * 128 + i4 * 4);
  ushort4 o;
  o.x = f2bf(v.x); o.y = f2bf(v.y); o.z = f2bf(v.z); o.w = f2bf(v.w);
  *(ushort4*)(Xt + (size_t)(t * 64 + b) * 128 + i4 * 4) = o;
}

// Wh fp32 -> bf16, pre-swizzled to the exact per-slice K-major LDS image:
// Whb[layer][slice][gate][o 0..63][c 0..31][j 0..7]  (49,152 shorts/slice).
// gru_rec then stages with straight int4 copies (no convert, no swizzle).
// Indexing formula-identical to the proven r11 in-kernel staging.
__global__ void whcvt_k(const float* __restrict__ Whz, const float* __restrict__ Whr,
                        const float* __restrict__ Whg, unsigned short* __restrict__ Whb) {
  int layer = blockIdx.x >> 4, slice = blockIdx.x & 15;
  const float* wsrc[3] = { Whz + (size_t)layer * 262144,
                           Whr + (size_t)layer * 262144,
                           Whg + (size_t)layer * 262144 };
  unsigned short* dst = Whb + (size_t)layer * 786432 + (size_t)slice * 49152;
  int cbase = slice * 32;
  for (int idx = threadIdx.x; idx < 12288; idx += 256) {
    int gate = idx >> 12, r = idx & 4095, c = r >> 7, k4 = r & 127;
    float4 v = *(const float4*)(wsrc[gate] + (size_t)(cbase + c) * 512 + k4 * 4);
    int o = k4 >> 1, base = (k4 & 1) * 4;
    ushort4 out;
    out.x = f2bf(v.x); out.y = f2bf(v.y); out.z = f2bf(v.z); out.w = f2bf(v.w);
    *(ushort4*)(dst + gate * 16384 + o * 256 + c * 8 + base) = out;
  }
}

// Poison all of a diagonal's targets in ONE dispatch: for each cell, the Hb
// chunk it will write (4 MB) + its U slot (4 MB). Grid = nc*512 blocks:
// cell = bid>>9; inner<256 -> Hb region, else U region; 256 blocks x 256
// threads x 8 u64 = 524,288 u64 = 4 MB per region. Agent-scope stores so
// poison is at the coherence point the polls read.
__global__ void poison3_k(unsigned long long* __restrict__ hb,
                          unsigned long long* __restrict__ ub, RecMeta meta) {
  const unsigned long long P = 0x7FC07FC07FC07FC0ull;
  int cell = blockIdx.x >> 9;
  int inner = blockIdx.x & 511;
  unsigned long long* base;
  if (inner < 256) {
    base = hb + (size_t)meta.ts[cell] * 8192;               // 32768 shorts/t = 8192 u64
  } else {
    base = ub + (size_t)meta.slot[cell] * (USLOT_SHORTS / 4);
    inner -= 256;
  }
  unsigned long long* p = base + (size_t)inner * 2048 + threadIdx.x;
#pragma unroll
  for (int k = 0; k < 8; k++)
    __hip_atomic_store(p + k * 256, P, __ATOMIC_RELAXED, __HIP_MEMORY_SCOPE_AGENT);
}

// ---------------------------------------------------------------------------
// gemm3: all three gate pre-activations in one dispatch (shared A).
// P{z,r,g}[M,512] = A[M,K] @ W{z,r,g}[512,K]^T, bf16 out.
// blockIdx.y in [0,12): gate = y>>2, n0 = (y&3)*128.   (proven r11)
// ---------------------------------------------------------------------------
__global__ __launch_bounds__(256)
void gemm3(const unsigned short* __restrict__ A,
           const unsigned short* __restrict__ Wz, const unsigned short* __restrict__ Wr,
           const unsigned short* __restrict__ Wg,
           unsigned short* __restrict__ Pz, unsigned short* __restrict__ Pr,
           unsigned short* __restrict__ Pg,
           int M, int K) {
  __shared__ unsigned short As[128][72];
  __shared__ unsigned short Bs[128][72];
  const int gate = blockIdx.y >> 2;
  const unsigned short* W = (gate == 0) ? Wz : (gate == 1) ? Wr : Wg;
  unsigned short* C       = (gate == 0) ? Pz : (gate == 1) ? Pr : Pg;
  const int tid  = threadIdx.x;
  const int lane = tid & 63;
  const int wave = tid >> 6;
  const int wr = wave >> 1, wc = wave & 1;
  const int m0 = blockIdx.x * 128, n0 = (blockIdx.y & 3) * 128;

  f32x4 acc[4][4];
  for (int i = 0; i < 4; i++)
    for (int j = 0; j < 4; j++) acc[i][j] = f32x4{0.f, 0.f, 0.f, 0.f};

  for (int k0 = 0; k0 < K; k0 += 64) {
    int4 va[4], vb[4];
#pragma unroll
    for (int it = 0; it < 4; it++) {
      int q = tid + it * 256;
      int r = q >> 3, kc = q & 7;
      va[it] = *(const int4*)(A + (size_t)(m0 + r) * K + k0 + kc * 8);
      vb[it] = *(const int4*)(W + (size_t)(n0 + r) * K + k0 + kc * 8);
    }
    __syncthreads();
#pragma unroll
    for (int it = 0; it < 4; it++) {
      int q = tid + it * 256;
      int r = q >> 3, kc = q & 7;
      *(int4*)&As[r][kc * 8] = va[it];
      *(int4*)&Bs[r][kc * 8] = vb[it];
    }
    __syncthreads();
#pragma unroll
    for (int kc = 0; kc < 2; kc++) {
      int koff = kc * 32 + (lane >> 4) * 8;
      int4 af[4], bfr[4];
#pragma unroll
      for (int mt = 0; mt < 4; mt++) af[mt]  = *(const int4*)&As[wr * 64 + mt * 16 + (lane & 15)][koff];
#pragma unroll
      for (int nt = 0; nt < 4; nt++) bfr[nt] = *(const int4*)&Bs[wc * 64 + nt * 16 + (lane & 15)][koff];
#pragma unroll
      for (int mt = 0; mt < 4; mt++)
#pragma unroll
        for (int nt = 0; nt < 4; nt++)
          acc[mt][nt] = mfma16(af[mt], bfr[nt], acc[mt][nt]);
    }
  }

#pragma unroll
  for (int mt = 0; mt < 4; mt++)
#pragma unroll
    for (int nt = 0; nt < 4; nt++)
#pragma unroll
      for (int rg = 0; rg < 4; rg++) {
        int m = m0 + wr * 64 + mt * 16 + (lane >> 4) * 4 + rg;
        int n = n0 + wc * 64 + nt * 16 + (lane & 15);
        C[(size_t)m * 512 + n] = f2bf(acc[mt][nt][rg]);
      }
}

// ---------------------------------------------------------------------------
// C[M,N] = A[M,K] @ W[N,K]^T, fp32 out + bias, row remap m=(t*64+b) -> out
// row b*1024+t. Used for the final Y projection only.   (proven)
// ---------------------------------------------------------------------------
__global__ __launch_bounds__(256)
void gemm_bt(const unsigned short* __restrict__ A, const unsigned short* __restrict__ W,
             float* __restrict__ Cout, const float* __restrict__ bias,
             int M, int N, int K) {
  __shared__ unsigned short As[128][72];
  __shared__ unsigned short Bs[128][72];
  const int tid  = threadIdx.x;
  const int lane = tid & 63;
  const int wave = tid >> 6;
  const int wr = wave >> 1, wc = wave & 1;
  const int m0 = blockIdx.x * 128, n0 = blockIdx.y * 128;

  f32x4 acc[4][4];
  for (int i = 0; i < 4; i++)
    for (int j = 0; j < 4; j++) acc[i][j] = f32x4{0.f, 0.f, 0.f, 0.f};

  for (int k0 = 0; k0 < K; k0 += 64) {
    int4 va[4], vb[4];
#pragma unroll
    for (int it = 0; it < 4; it++) {
      int q = tid + it * 256;
      int r = q >> 3, kc = q & 7;
      va[it] = *(const int4*)(A + (size_t)(m0 + r) * K + k0 + kc * 8);
      vb[it] = *(const int4*)(W + (size_t)(n0 + r) * K + k0 + kc * 8);
    }
    __syncthreads();
#pragma unroll
    for (int it = 0; it < 4; it++) {
      int q = tid + it * 256;
      int r = q >> 3, kc = q & 7;
      *(int4*)&As[r][kc * 8] = va[it];
      *(int4*)&Bs[r][kc * 8] = vb[it];
    }
    __syncthreads();
#pragma unroll
    for (int kc = 0; kc < 2; kc++) {
      int koff = kc * 32 + (lane >> 4) * 8;
      int4 af[4], bfr[4];
#pragma unroll
      for (int mt = 0; mt < 4; mt++) af[mt]  = *(const int4*)&As[wr * 64 + mt * 16 + (lane & 15)][koff];
#pragma unroll
      for (int nt = 0; nt < 4; nt++) bfr[nt] = *(const int4*)&Bs[wc * 64 + nt * 16 + (lane & 15)][koff];
#pragma unroll
      for (int mt = 0; mt < 4; mt++)
#pragma unroll
        for (int nt = 0; nt < 4; nt++)
          acc[mt][nt] = mfma16(af[mt], bfr[nt], acc[mt][nt]);
    }
  }

#pragma unroll
  for (int mt = 0; mt < 4; mt++)
#pragma unroll
    for (int nt = 0; nt < 4; nt++)
#pragma unroll
      for (int rg = 0; rg < 4; rg++) {
        int m = m0 + wr * 64 + mt * 16 + (lane >> 4) * 4 + rg;
        int n = n0 + wc * 64 + nt * 16 + (lane & 15);
        Cout[(size_t)((m & 63) * 1024 + (m >> 6)) * N + n] = acc[mt][nt][rg] + bias[n];
      }
}

// ---------------------------------------------------------------------------
// Recurrence: up to 3 independent (layer,chunk) cells per dispatch.
// Cell = blockIdx.x>>6 (64 WGs each = 4 batch-groups x 16 col-slices).
// r15: r11-proven poll; Wh staged from pre-swizzled image; CT=64.
// ---------------------------------------------------------------------------
__global__ __launch_bounds__(128)
void gru_rec(const unsigned short* __restrict__ Whb,  // pre-swizzled bf16 Wh
             const float* __restrict__ bz, const float* __restrict__ br,
             const float* __restrict__ bg,
             const unsigned short* __restrict__ PzB, const unsigned short* __restrict__ PrB,
             const unsigned short* __restrict__ PgB, // slot-strided bases
             const float* __restrict__ h0,           // (B,L,H) fp32 original
             float* __restrict__ hstateB,            // per-layer (B,H) fp32 carries
             unsigned short* __restrict__ Hbuf,      // (S,B,H) bf16, per-t slots (poisoned)
             unsigned short* __restrict__ UbufB,     // slot-strided (CT,B,H) bf16 (poisoned)
             float* __restrict__ hidout,             // (B,L,H) fp32
             RecMeta meta) {
  const int cell = blockIdx.x >> 6;
  const int bid  = blockIdx.x & 63;
  const int layer  = meta.l[cell];
  const int tstart = meta.ts[cell];
  const int slot   = meta.slot[cell];
  const unsigned short* Pz = PzB + (size_t)slot * PSLOT_SHORTS;
  const unsigned short* Pr = PrB + (size_t)slot * PSLOT_SHORTS;
  const unsigned short* Pg = PgB + (size_t)slot * PSLOT_SHORTS;
  unsigned short* Ubuf     = UbufB + (size_t)slot * USLOT_SHORTS;
  float* hstate            = hstateB + (size_t)layer * 32768;

  const int g    = bid & 3;          // batch group (16 rows)
  const int mem  = bid >> 2;         // col slice 0..15
  const int cbase = mem * CC;
  const int tid  = threadIdx.x;
  const int lane = tid & 63;
  const int wave = tid >> 6;         // 0..1

  // K-major weight LDS: [gate 0=z,1=r,2=g][K-octet 0..63][col 0..31][8 bf16]
  __shared__ __align__(16) unsigned short Whs[3][64][32][8];   // 98,304 B
  __shared__ float hloc[16][CC + 1];
  __shared__ float zbuf[16][CC + 1];
  __shared__ unsigned short un[16][40];
  __shared__ unsigned short hnew[16][40];

  // ---- stage pre-swizzled Wh image: straight int4 copies ----
  {
    const unsigned short* src = Whb + (size_t)layer * 786432 + (size_t)mem * 49152;
    unsigned short* ds = &Whs[0][0][0][0];
    for (int i = tid; i < 6144; i += 128)
      *(int4*)(ds + (size_t)i * 8) = *(const int4*)(src + (size_t)i * 8);
  }
  // ---- init local h slice (fp32) -- no broadcast needed at tl==0 ----
  for (int q = tid; q < 16 * CC; q += 128) {
    int row = q >> 5, c = q & 31;
    int b = g * 16 + row;
    hloc[row][c] = (tstart == 0)
                     ? h0[(size_t)b * 1536 + layer * 512 + cbase + c]
                     : hstate[(size_t)b * 512 + cbase + c];
  }
  __syncthreads();

  const int l15 = lane & 15;
  const int kq  = lane >> 4;

  float bzc[2], brc[2], bgc[2];
#pragma unroll
  for (int T = 0; T < 2; T++) {
    bzc[T] = bz[(size_t)layer * 512 + cbase + T * 16 + l15];
    brc[T] = br[(size_t)layer * 512 + cbase + T * 16 + l15];
    bgc[T] = bg[(size_t)layer * 512 + cbase + T * 16 + l15];
  }

  for (int tl = 0; tl < CT; tl++) {
    if (wave == 0) {
      // ---- prefetch P (cached, independent of h) ----
      float pr[2][4], pz[2][4];
#pragma unroll
      for (int T = 0; T < 2; T++)
#pragma unroll
        for (int rg = 0; rg < 4; rg++) {
          size_t off = (size_t)tl * 32768 + (size_t)(g * 16 + kq * 4 + rg) * 512 + cbase + T * 16 + l15;
          pr[T][rg] = bf2f(Pr[off]);
          pz[T][rg] = bf2f(Pz[off]);
        }
      // ---- acquire h(t-1) fragments ----
      int4 hf[16];
      if (tl == 0) {
        const float* hs = (tstart == 0)
                            ? h0 + (size_t)(g * 16 + l15) * 1536 + (size_t)layer * 512
                            : hstate + (size_t)(g * 16 + l15) * 512;
#pragma unroll
        for (int kc = 0; kc < 16; kc++) {
          int c0 = kq * 8 + kc * 32;
          float4 v0 = *(const float4*)(hs + c0);
          float4 v1 = *(const float4*)(hs + c0 + 4);
          int w0 = (int)f2bf(v0.x) | ((int)f2bf(v0.y) << 16);
          int w1 = (int)f2bf(v0.z) | ((int)f2bf(v0.w) << 16);
          int w2 = (int)f2bf(v1.x) | ((int)f2bf(v1.y) << 16);
          int w3 = (int)f2bf(v1.z) | ((int)f2bf(v1.w) << 16);
          hf[kc] = int4{w0, w1, w2, w3};
        }
      } else {
        poll_slab16(Hbuf + (size_t)(tstart + tl - 1) * 32768 + (g * 16 + l15) * 512 + kq * 8, hf);
      }
      // ---- r gate first (feeds the u-hop) ----
      f32x4 ar[2] = { f32x4{0.f,0.f,0.f,0.f}, f32x4{0.f,0.f,0.f,0.f} };
#pragma unroll
      for (int kc = 0; kc < 16; kc++)
#pragma unroll
        for (int T = 0; T < 2; T++)
          ar[T] = mfma16(hf[kc], *(const int4*)&Whs[1][kc * 4 + kq][T * 16 + l15][0], ar[T]);
#pragma unroll
      for (int T = 0; T < 2; T++)
#pragma unroll
        for (int rg = 0; rg < 4; rg++) {
          int row = kq * 4 + rg, c = T * 16 + l15;
          float rv = sig_(ar[T][rg] + pr[T][rg] + brc[T]);
          un[row][c] = f2bf(rv * hloc[row][c]);
        }
      // coalesced u publish; value IS the flag
      {
        int4 v = *(const int4*)&un[lane >> 2][(lane & 3) * 8];
        st_wt128(Ubuf + (size_t)tl * 32768 + (g * 16 + (lane >> 2)) * 512 + cbase + (lane & 3) * 8, v);
      }
      // ---- z gate (off the u critical path; store drains in background) ----
      f32x4 az[2] = { f32x4{0.f,0.f,0.f,0.f}, f32x4{0.f,0.f,0.f,0.f} };
#pragma unroll
      for (int kc = 0; kc < 16; kc++)
#pragma unroll
        for (int T = 0; T < 2; T++)
          az[T] = mfma16(hf[kc], *(const int4*)&Whs[0][kc * 4 + kq][T * 16 + l15][0], az[T]);
#pragma unroll
      for (int T = 0; T < 2; T++)
#pragma unroll
        for (int rg = 0; rg < 4; rg++)
          zbuf[kq * 4 + rg][T * 16 + l15] = sig_(az[T][rg] + pz[T][rg] + bzc[T]);
    } else {
      // ---- prefetch Pg ----
      float pg[2][4];
#pragma unroll
      for (int T = 0; T < 2; T++)
#pragma unroll
        for (int rg = 0; rg < 4; rg++)
          pg[T][rg] = bf2f(Pg[(size_t)tl * 32768 + (size_t)(g * 16 + kq * 4 + rg) * 512 + cbase + T * 16 + l15]);
      // ---- acquire u(t): data-as-flag poll ----
      int4 uf[16];
      poll_slab16(Ubuf + (size_t)tl * 32768 + (g * 16 + l15) * 512 + kq * 8, uf);
      f32x4 ag[2] = { f32x4{0.f,0.f,0.f,0.f}, f32x4{0.f,0.f,0.f,0.f} };
#pragma unroll
      for (int kc = 0; kc < 16; kc++)
#pragma unroll
        for (int T = 0; T < 2; T++)
          ag[T] = mfma16(uf[kc], *(const int4*)&Whs[2][kc * 4 + kq][T * 16 + l15][0], ag[T]);
#pragma unroll
      for (int T = 0; T < 2; T++)
#pragma unroll
        for (int rg = 0; rg < 4; rg++)
          ag[T][rg] += pg[T][rg] + bgc[T];
      __syncthreads();   // A: zbuf ready (wave0 wrote it pre-barrier)
#pragma unroll
      for (int T = 0; T < 2; T++)
#pragma unroll
        for (int rg = 0; rg < 4; rg++) {
          int row = kq * 4 + rg, c = T * 16 + l15;
          float gv = tanh_(ag[T][rg]);
          float z  = zbuf[row][c];
          float h  = hloc[row][c];
          float hn = z * h + (1.0f - z) * gv;
          hloc[row][c] = hn;
          hnew[row][c] = f2bf(hn);
        }
      // coalesced h publish; value IS the flag
      {
        int4 v = *(const int4*)&hnew[lane >> 2][(lane & 3) * 8];
        st_wt128(&Hbuf[(size_t)(tstart + tl) * 32768 + (g * 16 + (lane >> 2)) * 512 + cbase + (lane & 3) * 8], v);
      }
    }
    if (wave == 0) __syncthreads();  // A (wave0 side)
    __syncthreads();                 // B: hloc/zbuf safe for next step
  }

  // ---- chunk carry-out ----
  for (int q = tid; q < 16 * CC; q += 128) {
    int row = q >> 5, c = q & 31;
    int b = g * 16 + row;
    float v = hloc[row][c];
    hstate[(size_t)b * 512 + cbase + c] = v;
    if (tstart + CT == 1024)
      hidout[(size_t)b * 1536 + layer * 512 + cbase + c] = v;
  }
}

// ---------------------------------------------------------------------------
// launcher
// ---------------------------------------------------------------------------
extern "C" void kernel_launch(void* const* d_in, const int* in_sizes, int n_in,
                              void* d_out, int out_size, void* d_ws, size_t ws_size,
                              hipStream_t stream) {
  const float* X    = (const float*)d_in[0];
  const float* H0   = (const float*)d_in[1];
  const float* Wx0z = (const float*)d_in[2];
  const float* Wx0r = (const float*)d_in[3];
  const float* Wx0g = (const float*)d_in[4];
  const float* Wxz  = (const float*)d_in[5];
  const float* Wxr  = (const float*)d_in[6];
  const float* Wxg  = (const float*)d_in[7];
  const float* Whz  = (const float*)d_in[8];
  const float* Whr  = (const float*)d_in[9];
  const float* Whg  = (const float*)d_in[10];
  const float* bz   = (const float*)d_in[11];
  const float* br   = (const float*)d_in[12];
  const float* bg   = (const float*)d_in[13];
  const float* Wy   = (const float*)d_in[14];
  const float* by   = (const float*)d_in[15];

  // ---- workspace tiering ----
  // need(n) = 20,447,232 (head) + n*12,582,912 (P) + 67,108,864 (Hb)
  //           + 393,216 (hst x3) + n*4,194,304 (U) + 4,718,592 (Whb)
  // n=3: 142,999,552   n=1: 109,445,120
  int nslot = (ws_size >= 142999552ull) ? 3 : 1;

  char* w = (char*)d_ws;
  unsigned short* Xt    = (unsigned short*)(w + 0);          // 16,777,216
  unsigned short* Wx0zb = (unsigned short*)(w + 16777216);
  unsigned short* Wx0rb = (unsigned short*)(w + 16908288);
  unsigned short* Wx0gb = (unsigned short*)(w + 17039360);
  unsigned short* Wxzb  = (unsigned short*)(w + 17170432);
  unsigned short* Wxrb  = (unsigned short*)(w + 18219008);
  unsigned short* Wxgb  = (unsigned short*)(w + 19267584);
  unsigned short* Wyb   = (unsigned short*)(w + 20316160);
  const size_t off = 20447232;           // start of slot-strided P region
  unsigned short* PzB = (unsigned short*)(w + off);
  unsigned short* PrB = (unsigned short*)(w + off + PGATE_BYTES);
  unsigned short* PgB = (unsigned short*)(w + off + 2 * PGATE_BYTES);
  size_t hbOff  = off + (size_t)nslot * (PSLOT_SHORTS * 2);
  unsigned short* Hb  = (unsigned short*)(w + hbOff);        // 67,108,864
  size_t hstOff = hbOff + 67108864;
  float* hst          = (float*)(w + hstOff);                // 3 x 131,072
  size_t uOff   = hstOff + 393216;
  unsigned short* UbB = (unsigned short*)(w + uOff);         // nslot x 4,194,304
  size_t whbOff = uOff + (size_t)nslot * (USLOT_SHORTS * 2);
  unsigned short* Whb = (unsigned short*)(w + whbOff);       // 4,718,592

  auto cvt = [&](const float* s, unsigned short* d, int n) {
    int n4 = n / 4;
    cvt_bf16<<<dim3((n4 + 255) / 256), dim3(256), 0, stream>>>(s, d, n4);
  };
  xt_k<<<dim3(8192), dim3(256), 0, stream>>>(X, Xt);
  cvt(Wx0z, Wx0zb, 65536);
  cvt(Wx0r, Wx0rb, 65536);
  cvt(Wx0g, Wx0gb, 65536);
  cvt(Wxz, Wxzb, 524288);
  cvt(Wxr, Wxrb, 524288);
  cvt(Wxg, Wxgb, 524288);
  cvt(Wy, Wyb, 65536);
  whcvt_k<<<dim3(48), dim3(256), 0, stream>>>(Whz, Whr, Whg, Whb);

  float* hidout = (float*)d_out + 8388608;

  // ---- wavefront schedule over the 3 x 16 (layer,chunk) grid ----
  // diagonal d holds cells (l, d-l), width <= 3; deps: (l,c) <- (l,c-1)
  // [hstate, earlier diagonal], (l-1,c) [Hb chunk c via gemm3 this diagonal].
  const int ndisp = (nslot == 3) ? (NCHUNK + 2) : (3 * NCHUNK);

  for (int d = 0; d < ndisp; d++) {
    RecMeta meta{};
    int cl[3], cch[3];
    int nc = 0;
    if (nslot == 3) {
      for (int l = 0; l < 3; l++) {
        int c = d - l;
        if (c >= 0 && c < NCHUNK) { cl[nc] = l; cch[nc] = c; nc++; }
      }
    } else {
      cl[0] = d / NCHUNK; cch[0] = d % NCHUNK; nc = 1;
    }
    // phase 1: fused 3-gate GEMMs (read prev-layer Hb, write per-slot P)
    for (int s = 0; s < nc; s++) {
      int layer = cl[s], tstart = cch[s] * CT;
      const unsigned short *Ap, *wz, *wr_, *wg;
      int K;
      if (layer == 0) {
        Ap = Xt + (size_t)tstart * 64 * 128;
        wz = Wx0zb; wr_ = Wx0rb; wg = Wx0gb; K = 128;
      } else {
        Ap = Hb + (size_t)tstart * 32768;
        wz = Wxzb + (size_t)(layer - 1) * 262144;
        wr_ = Wxrb + (size_t)(layer - 1) * 262144;
        wg = Wxgb + (size_t)(layer - 1) * 262144;
        K = 512;
      }
      gemm3<<<dim3(CT * 64 / 128, 12), 256, 0, stream>>>(
          Ap, wz, wr_, wg,
          PzB + (size_t)s * PSLOT_SHORTS,
          PrB + (size_t)s * PSLOT_SHORTS,
          PgB + (size_t)s * PSLOT_SHORTS,
          CT * 64, K);
      meta.l[s] = layer; meta.ts[s] = tstart; meta.slot[s] = s;
    }
    // phase 2: one dispatch poisons all Hb chunks to be written + U slots
    poison3_k<<<dim3(nc * 512), dim3(256), 0, stream>>>(
        (unsigned long long*)Hb, (unsigned long long*)UbB, meta);
    // phase 3: concurrent independent recurrence cells
    gru_rec<<<dim3(nc * 64), dim3(128), 0, stream>>>(
        Whb, bz, br, bg, PzB, PrB, PgB, H0, hst, Hb, UbB,
        hidout, meta);
  }

  // Y = H2 @ Wy^T + by  -> (B,S,O) fp32
  gemm_bt<<<dim3(512, 1), 256, 0, stream>>>(Hb, Wyb, (float*)d_out, by, 65536, 128, 512);
}